// Round 1
// baseline (1257.689 us; speedup 1.0000x reference)
//
#include <hip/hip_runtime.h>
#include <cmath>

// ---------------------------------------------------------------------------
// TransformerLayer: out = relu((softmax((Y W^T)(Y W^T)^T) @ Y) @ Wfe + B)
//   Wfe = -0.5*(Wf + Wf^T);  n=4096, d=1024, fp32.
// Round 1: correctness-first fp32 vector baseline (no fp32 MFMA on CDNA4).
// ---------------------------------------------------------------------------

#define TLBM 128
#define TLBN 128
#define TLBK 16
#define TLPAD 4   // pad so LDS row stride = 132 floats (16B-aligned, bank-spread)

// C[M,N] = A[M,K] @ B  (B is [K,N] if !TRANS_B, [N,K] if TRANS_B -> C = A*B^T)
// Optional epilogue: C = relu(C + bias[col])
template<bool TRANS_B, bool BIAS_RELU>
__global__ __launch_bounds__(256, 2)
void gemm_f32_kernel(const float* __restrict__ A, const float* __restrict__ B,
                     const float* __restrict__ bias, float* __restrict__ C,
                     int M, int N, int K)
{
    __shared__ float As[TLBK][TLBM + TLPAD];  // k-major: As[k][m]
    __shared__ float Bs[TLBK][TLBN + TLPAD];  // k-major: Bs[k][n]

    const int tid = threadIdx.x;
    const int tx  = tid & 15;   // column group (0..15)
    const int ty  = tid >> 4;   // row group    (0..15)
    const int bm  = blockIdx.y * TLBM;
    const int bn  = blockIdx.x * TLBN;

    float acc[8][8];
#pragma unroll
    for (int i = 0; i < 8; ++i)
#pragma unroll
        for (int j = 0; j < 8; ++j) acc[i][j] = 0.f;

    // staging indices (transposed A / transposed-B loads): 256 thr * 2 halves
    const int srow = tid >> 2;        // 0..63
    const int scol = (tid & 3) * 4;   // 0,4,8,12

    for (int k0 = 0; k0 < K; k0 += TLBK) {
        // --- stage A tile: As[k][m] = A[bm+m][k0+k] ---
#pragma unroll
        for (int half = 0; half < 2; ++half) {
            const int m = srow + half * 64;
            const float4 a4 = *reinterpret_cast<const float4*>(
                &A[(size_t)(bm + m) * K + k0 + scol]);
            As[scol + 0][m] = a4.x;
            As[scol + 1][m] = a4.y;
            As[scol + 2][m] = a4.z;
            As[scol + 3][m] = a4.w;
        }
        // --- stage B tile: Bs[k][n] ---
        if (TRANS_B) {
#pragma unroll
            for (int half = 0; half < 2; ++half) {
                const int nn = srow + half * 64;
                const float4 b4 = *reinterpret_cast<const float4*>(
                    &B[(size_t)(bn + nn) * K + k0 + scol]);
                Bs[scol + 0][nn] = b4.x;
                Bs[scol + 1][nn] = b4.y;
                Bs[scol + 2][nn] = b4.z;
                Bs[scol + 3][nn] = b4.w;
            }
        } else {
            const int krow = tid >> 5;        // 0..7
            const int ncol = (tid & 31) * 4;  // 0..124
#pragma unroll
            for (int half = 0; half < 2; ++half) {
                const int k = krow + half * 8;
                const float4 b4 = *reinterpret_cast<const float4*>(
                    &B[(size_t)(k0 + k) * N + bn + ncol]);
                *reinterpret_cast<float4*>(&Bs[k][ncol]) = b4;
            }
        }
        __syncthreads();

        // --- inner product over the K-tile ---
#pragma unroll
        for (int kk = 0; kk < TLBK; ++kk) {
            float af[8], bf[8];
#pragma unroll
            for (int i = 0; i < 8; ++i) af[i] = As[kk][ty * 8 + i];
#pragma unroll
            for (int j = 0; j < 8; ++j) bf[j] = Bs[kk][tx * 8 + j];
#pragma unroll
            for (int i = 0; i < 8; ++i)
#pragma unroll
                for (int j = 0; j < 8; ++j)
                    acc[i][j] = fmaf(af[i], bf[j], acc[i][j]);
        }
        __syncthreads();
    }

    // --- epilogue ---
#pragma unroll
    for (int i = 0; i < 8; ++i) {
        const int row  = bm + ty * 8 + i;
        const int col0 = bn + tx * 8;
        float o[8];
#pragma unroll
        for (int j = 0; j < 8; ++j) o[j] = acc[i][j];
        if (BIAS_RELU) {
#pragma unroll
            for (int j = 0; j < 8; ++j) {
                o[j] = o[j] + bias[col0 + j];
                o[j] = fmaxf(o[j], 0.f);
            }
        }
        float4* dst = reinterpret_cast<float4*>(&C[(size_t)row * N + col0]);
        dst[0] = make_float4(o[0], o[1], o[2], o[3]);
        dst[1] = make_float4(o[4], o[5], o[6], o[7]);
    }
}

// Row-wise softmax, in place. One block (256 thr) per row of length n=4096;
// each thread owns 16 elements (4 lane-contiguous float4 slices) in registers.
__global__ __launch_bounds__(256)
void softmax_rows_kernel(float* __restrict__ S, int n)
{
    const int row = blockIdx.x;
    float4* p = reinterpret_cast<float4*>(S + (size_t)row * n);
    const int t = threadIdx.x;

    float4 v[4];
    float mx = -3.402823466e38f;
#pragma unroll
    for (int i = 0; i < 4; ++i) {
        v[i] = p[t + i * 256];
        mx = fmaxf(mx, fmaxf(fmaxf(v[i].x, v[i].y), fmaxf(v[i].z, v[i].w)));
    }
#pragma unroll
    for (int off = 32; off > 0; off >>= 1) mx = fmaxf(mx, __shfl_xor(mx, off));

    __shared__ float redmax[4];
    __shared__ float redsum[4];
    const int wave = t >> 6, lane = t & 63;
    if (lane == 0) redmax[wave] = mx;
    __syncthreads();
    mx = fmaxf(fmaxf(redmax[0], redmax[1]), fmaxf(redmax[2], redmax[3]));

    float sum = 0.f;
#pragma unroll
    for (int i = 0; i < 4; ++i) {
        v[i].x = __expf(v[i].x - mx); sum += v[i].x;
        v[i].y = __expf(v[i].y - mx); sum += v[i].y;
        v[i].z = __expf(v[i].z - mx); sum += v[i].z;
        v[i].w = __expf(v[i].w - mx); sum += v[i].w;
    }
#pragma unroll
    for (int off = 32; off > 0; off >>= 1) sum += __shfl_xor(sum, off);
    if (lane == 0) redsum[wave] = sum;
    __syncthreads();
    sum = redsum[0] + redsum[1] + redsum[2] + redsum[3];

    const float inv = 1.f / sum;
#pragma unroll
    for (int i = 0; i < 4; ++i) {
        v[i].x *= inv; v[i].y *= inv; v[i].z *= inv; v[i].w *= inv;
        p[t + i * 256] = v[i];
    }
}

// Wfe[i][j] = -0.5*(Wf[i][j] + Wf[j][i])   (alpha_2 = 1 -> identity term is 0)
__global__ __launch_bounds__(256)
void symm_kernel(const float* __restrict__ Wf, float* __restrict__ Wfe, int d)
{
    const int j = blockIdx.x * 256 + threadIdx.x;
    const int i = blockIdx.y;
    Wfe[(size_t)i * d + j] = -0.5f * (Wf[(size_t)i * d + j] + Wf[(size_t)j * d + i]);
}

extern "C" void kernel_launch(void* const* d_in, const int* in_sizes, int n_in,
                              void* d_out, int out_size, void* d_ws, size_t ws_size,
                              hipStream_t stream)
{
    const float* Y  = (const float*)d_in[0];   // (4096, 1024)
    const float* W  = (const float*)d_in[1];   // (1024, 1024)
    const float* Wf = (const float*)d_in[2];   // (1024, 1024)
    const float* Bb = (const float*)d_in[3];   // (1, 1024)
    float* out = (float*)d_out;                // (4096, 1024)

    const int n = 4096, d = 1024;

    // workspace layout (floats): YWt | S | Z | Wfe  => ~100 MB total
    float* YWt = (float*)d_ws;
    float* S   = YWt + (size_t)n * d;
    float* Z   = S   + (size_t)n * n;
    float* Wfe = Z   + (size_t)n * d;

    const dim3 blk(256);

    // 1) YWt = Y @ W^T                     (M=4096, N=1024, K=1024)
    gemm_f32_kernel<true, false><<<dim3(d / TLBN, n / TLBM), blk, 0, stream>>>(
        Y, W, nullptr, YWt, n, d, d);

    // 2) S = YWt @ YWt^T                   (M=4096, N=4096, K=1024)
    gemm_f32_kernel<true, false><<<dim3(n / TLBN, n / TLBM), blk, 0, stream>>>(
        YWt, YWt, nullptr, S, n, n, d);

    // 3) A = softmax(S) rows, in place
    softmax_rows_kernel<<<dim3(n), blk, 0, stream>>>(S, n);

    // 4) Z = A @ Y                         (M=4096, N=1024, K=4096)
    gemm_f32_kernel<false, false><<<dim3(d / TLBN, n / TLBM), blk, 0, stream>>>(
        S, Y, nullptr, Z, n, d, n);

    // 5) Wfe = -0.5*(Wf + Wf^T)
    symm_kernel<<<dim3(d / 256, d), blk, 0, stream>>>(Wf, Wfe, d);

    // 6) out = relu(Z @ Wfe + B)           (M=4096, N=1024, K=1024)
    gemm_f32_kernel<false, true><<<dim3(d / TLBN, n / TLBM), blk, 0, stream>>>(
        Z, Wfe, Bb, out, n, d, d);
}

// Round 2
// 479.834 us; speedup vs baseline: 2.6211x; 2.6211x over previous
//
#include <hip/hip_runtime.h>
#include <cstdint>

// ---------------------------------------------------------------------------
// out = relu((softmax((Y W^T)(Y W^T)^T) @ Y) @ (-0.5(Wf+Wf^T)) + B)
// n=4096, d=1024, fp32 in/out.
// R2: split-precision bf16 MFMA GEMMs (hi/lo, 3-product), m97-style 128^2
// tiles, global_load_lds width-16, XOR-swizzled LDS, XCD tile swizzle.
// ---------------------------------------------------------------------------

typedef __attribute__((ext_vector_type(8))) short short8;
typedef __attribute__((ext_vector_type(4))) short short4v;
typedef __attribute__((ext_vector_type(4))) float f32x4;

__device__ __forceinline__ short f2bf(float x) {            // RNE fp32 -> bf16 bits
    unsigned u = __builtin_bit_cast(unsigned, x);
    u += 0x7fffu + ((u >> 16) & 1u);
    return (short)(u >> 16);
}
__device__ __forceinline__ float bf2f(short s) {
    unsigned u = ((unsigned)(unsigned short)s) << 16;
    return __builtin_bit_cast(float, u);
}

// async global->LDS, 16B per lane. LDS dest must be wave-uniform base + lane*16.
typedef const __attribute__((address_space(1))) void* gas1_t;
typedef __attribute__((address_space(3))) void* las3_t;
__device__ __forceinline__ void cp16(const void* g, void* l) {
    __builtin_amdgcn_global_load_lds((gas1_t)(uintptr_t)g, (las3_t)(uintptr_t)l, 16, 0, 0);
}

// ---------------------------------------------------------------------------
// Split-bf16 MFMA GEMM: C[M,N] = A[M,K] @ Bt[N,K]^T, A = Ahi+Alo, B = Bhi+Blo.
//   F32STAGE: A_, B_ are fp32; convert to hi/lo during staging (reg-staged).
//   BIASRELU: C = relu(acc + bias[col]) fp32; else C written as split bf16.
// 128x128 tile, BK=32, 4 waves (2x2 of 64x64), 16x16x32 bf16 MFMA.
// LDS XOR swizzle: physical 16B-chunk p at row r holds logical chunk p^((r>>1)&3).
// ---------------------------------------------------------------------------
template<bool F32STAGE, bool BIASRELU>
__global__ __launch_bounds__(256)
void mfma_gemm(const void* Ahi_, const void* Alo_,
               const void* Bhi_, const void* Blo_,
               const float* __restrict__ bias,
               void* Co_, void* Clo_,
               int M, int N, int K)
{
    __shared__ short lds[4][128 * 32];   // [Ahi][Alo][Bhi][Blo], 32 KB total

    const int tid  = threadIdx.x;
    const int lane = tid & 63;
    const int wave = tid >> 6;
    const int wr   = wave >> 1, wc = wave & 1;

    // XCD-aware tile swizzle (bijective: all our grids have nwg % 8 == 0)
    const int gx  = gridDim.x;
    const int nwg = gx * gridDim.y;
    const int lin = blockIdx.y * gx + blockIdx.x;
    int sw = lin;
    if ((nwg & 7) == 0) { const int cpx = nwg >> 3; sw = (lin & 7) * cpx + (lin >> 3); }
    const int bm = (sw / gx) * 128;
    const int bn = (sw % gx) * 128;

    f32x4 acc[4][4];
#pragma unroll
    for (int i = 0; i < 4; ++i)
#pragma unroll
        for (int j = 0; j < 4; ++j)
#pragma unroll
            for (int q = 0; q < 4; ++q) acc[i][j][q] = 0.f;

    // staging mapping: thread -> (row srow [+64 for half 1], physical chunk p)
    const int srow = tid >> 2;
    const int p    = tid & 3;
    const int csw  = p ^ ((tid >> 3) & 3);       // logical chunk (swizzle involution)

    // compute-side fragment byte offsets (in elements)
    const int fsw  = (((lane >> 4) ^ ((lane >> 1) & 3))) * 8;
    const int aoff = (wr * 64 + (lane & 15)) * 32 + fsw;
    const int boff = (wc * 64 + (lane & 15)) * 32 + fsw;

    const int nstep = K >> 5;

    // per-thread source pointers
    const short* s0; const short* s1; const short* s2; const short* s3;
    const short* s4; const short* s5; const short* s6; const short* s7;
    const float* fa0; const float* fa1; const float* fb0; const float* fb1;
    if (F32STAGE) {
        const float* A = (const float*)Ahi_;
        const float* B = (const float*)Bhi_;
        fa0 = A + (size_t)(bm + srow) * K + csw * 8;
        fa1 = fa0 + (size_t)64 * K;
        fb0 = B + (size_t)(bn + srow) * K + csw * 8;
        fb1 = fb0 + (size_t)64 * K;
        s0 = s1 = s2 = s3 = s4 = s5 = s6 = s7 = nullptr;
    } else {
        const size_t oA = (size_t)(bm + srow) * K + csw * 8;
        const size_t oB = (size_t)(bn + srow) * K + csw * 8;
        s0 = (const short*)Ahi_ + oA;  s1 = s0 + (size_t)64 * K;
        s2 = (const short*)Alo_ + oA;  s3 = s2 + (size_t)64 * K;
        s4 = (const short*)Bhi_ + oB;  s5 = s4 + (size_t)64 * K;
        s6 = (const short*)Blo_ + oB;  s7 = s6 + (size_t)64 * K;
        fa0 = fa1 = fb0 = fb1 = nullptr;
    }
    const int dbase = srow * 32 + p * 8;         // linear: == tid*8

    for (int step = 0; step < nstep; ++step) {
        __syncthreads();                         // previous tile fully consumed
        if (F32STAGE) {
#pragma unroll
            for (int q2 = 0; q2 < 4; ++q2) {
                const float* sp = (q2 == 0) ? fa0 : (q2 == 1) ? fa1 : (q2 == 2) ? fb0 : fb1;
                const float4 va = *(const float4*)sp;
                const float4 vb = *(const float4*)(sp + 4);
                const float f[8] = {va.x, va.y, va.z, va.w, vb.x, vb.y, vb.z, vb.w};
                short8 h8, l8;
#pragma unroll
                for (int j = 0; j < 8; ++j) {
                    const short hh = f2bf(f[j]);
                    h8[j] = hh;
                    l8[j] = f2bf(f[j] - bf2f(hh));
                }
                const int tb   = (q2 >= 2) ? 2 : 0;
                const int doff = (q2 & 1) * 2048 + dbase;
                *(short8*)&lds[tb + 0][doff] = h8;
                *(short8*)&lds[tb + 1][doff] = l8;
            }
            fa0 += 32; fa1 += 32; fb0 += 32; fb1 += 32;
        } else {
            cp16(s0, &lds[0][dbase]); cp16(s1, &lds[0][dbase + 2048]);
            cp16(s2, &lds[1][dbase]); cp16(s3, &lds[1][dbase + 2048]);
            cp16(s4, &lds[2][dbase]); cp16(s5, &lds[2][dbase + 2048]);
            cp16(s6, &lds[3][dbase]); cp16(s7, &lds[3][dbase + 2048]);
            s0 += 32; s1 += 32; s2 += 32; s3 += 32;
            s4 += 32; s5 += 32; s6 += 32; s7 += 32;
            asm volatile("s_waitcnt vmcnt(0)" ::: "memory");
        }
        __syncthreads();

        short8 fah[4], fal[4], fbh[4], fbl[4];
#pragma unroll
        for (int i = 0; i < 4; ++i) {
            fah[i] = *(const short8*)&lds[0][aoff + i * 512];
            fal[i] = *(const short8*)&lds[1][aoff + i * 512];
        }
#pragma unroll
        for (int j = 0; j < 4; ++j) {
            fbh[j] = *(const short8*)&lds[2][boff + j * 512];
            fbl[j] = *(const short8*)&lds[3][boff + j * 512];
        }
#pragma unroll
        for (int i = 0; i < 4; ++i)
#pragma unroll
            for (int j = 0; j < 4; ++j) {
                acc[i][j] = __builtin_amdgcn_mfma_f32_16x16x32_bf16(fah[i], fbh[j], acc[i][j], 0, 0, 0);
                acc[i][j] = __builtin_amdgcn_mfma_f32_16x16x32_bf16(fah[i], fbl[j], acc[i][j], 0, 0, 0);
                acc[i][j] = __builtin_amdgcn_mfma_f32_16x16x32_bf16(fal[i], fbh[j], acc[i][j], 0, 0, 0);
            }
    }

    // epilogue: C/D layout col = lane&15, row = (lane>>4)*4 + q  [m89-verified]
    const int crow0 = bm + wr * 64 + (lane >> 4) * 4;
    const int ccol0 = bn + wc * 64 + (lane & 15);
    if (BIASRELU) {
        float* C = (float*)Co_;
#pragma unroll
        for (int j = 0; j < 4; ++j) {
            const int c = ccol0 + j * 16;
            const float bv = bias[c];
#pragma unroll
            for (int i = 0; i < 4; ++i)
#pragma unroll
                for (int q = 0; q < 4; ++q) {
                    const int r = crow0 + i * 16 + q;
                    C[(size_t)r * N + c] = fmaxf(acc[i][j][q] + bv, 0.f);
                }
        }
    } else {
        short* Ch = (short*)Co_;
        short* Cl = (short*)Clo_;
#pragma unroll
        for (int j = 0; j < 4; ++j) {
            const int c = ccol0 + j * 16;
#pragma unroll
            for (int i = 0; i < 4; ++i)
#pragma unroll
                for (int q = 0; q < 4; ++q) {
                    const int r = crow0 + i * 16 + q;
                    const float v = acc[i][j][q];
                    const short hh = f2bf(v);
                    Ch[(size_t)r * N + c] = hh;
                    Cl[(size_t)r * N + c] = f2bf(v - bf2f(hh));
                }
        }
    }
}

// ---------------------------------------------------------------------------
// Row softmax over split logits, in place (row r touches only row r). n=4096.
// ---------------------------------------------------------------------------
__global__ __launch_bounds__(256)
void softmax_split_inplace(short* __restrict__ Shi, short* __restrict__ Slo)
{
    const int row = blockIdx.x;
    short8* ph = (short8*)(Shi + (size_t)row * 4096);
    short8* pl = (short8*)(Slo + (size_t)row * 4096);
    const int t = threadIdx.x;

    short8 h0 = ph[t], h1 = ph[t + 256];
    short8 l0 = pl[t], l1 = pl[t + 256];
    float x[16];
#pragma unroll
    for (int j = 0; j < 8; ++j) {
        x[j]     = bf2f(h0[j]) + bf2f(l0[j]);
        x[8 + j] = bf2f(h1[j]) + bf2f(l1[j]);
    }
    float mx = x[0];
#pragma unroll
    for (int j = 1; j < 16; ++j) mx = fmaxf(mx, x[j]);
#pragma unroll
    for (int off = 32; off > 0; off >>= 1) mx = fmaxf(mx, __shfl_xor(mx, off));

    __shared__ float rm[4], rs[4];
    const int wv = t >> 6, ln = t & 63;
    if (ln == 0) rm[wv] = mx;
    __syncthreads();
    mx = fmaxf(fmaxf(rm[0], rm[1]), fmaxf(rm[2], rm[3]));

    float s = 0.f;
#pragma unroll
    for (int j = 0; j < 16; ++j) { x[j] = __expf(x[j] - mx); s += x[j]; }
#pragma unroll
    for (int off = 32; off > 0; off >>= 1) s += __shfl_xor(s, off);
    if (ln == 0) rs[wv] = s;
    __syncthreads();
    s = rs[0] + rs[1] + rs[2] + rs[3];

    const float inv = 1.f / s;
#pragma unroll
    for (int j = 0; j < 8; ++j) {
        float ya = x[j] * inv;
        short ha = f2bf(ya);
        h0[j] = ha; l0[j] = f2bf(ya - bf2f(ha));
        float yb = x[8 + j] * inv;
        short hb = f2bf(yb);
        h1[j] = hb; l1[j] = f2bf(yb - bf2f(hb));
    }
    ph[t] = h0; ph[t + 256] = h1;
    pl[t] = l0; pl[t + 256] = l1;
}

// ---------------------------------------------------------------------------
// Yt = Y^T as split bf16. Y: [4096][1024] fp32 -> Ythi/Ytlo: [1024][4096].
// ---------------------------------------------------------------------------
__global__ __launch_bounds__(256)
void transpose_split(const float* __restrict__ Y, short* __restrict__ Th, short* __restrict__ Tl)
{
    __shared__ float tb[64][65];
    const int rb = blockIdx.y * 64, cb = blockIdx.x * 64;
    const int t = threadIdx.x;
    const int r = t >> 4, c4 = (t & 15) * 4;
#pragma unroll
    for (int it = 0; it < 4; ++it) {
        const float4 v = *(const float4*)&Y[(size_t)(rb + r + it * 16) * 1024 + cb + c4];
        tb[r + it * 16][c4 + 0] = v.x; tb[r + it * 16][c4 + 1] = v.y;
        tb[r + it * 16][c4 + 2] = v.z; tb[r + it * 16][c4 + 3] = v.w;
    }
    __syncthreads();
    const int orow = t >> 2;            // Yt row within tile (= Y col)
    const int oc0  = (t & 3) * 16;      // Yt col within tile (= Y row)
    short8 h[2], l[2];
#pragma unroll
    for (int g = 0; g < 2; ++g)
#pragma unroll
        for (int j = 0; j < 8; ++j) {
            const float v = tb[oc0 + g * 8 + j][orow];
            const short hh = f2bf(v);
            h[g][j] = hh;
            l[g][j] = f2bf(v - bf2f(hh));
        }
    const size_t ob = (size_t)(cb + orow) * 4096 + rb + oc0;
    *(short8*)&Th[ob] = h[0]; *(short8*)&Th[ob + 8] = h[1];
    *(short8*)&Tl[ob] = l[0]; *(short8*)&Tl[ob + 8] = l[1];
}

// ---------------------------------------------------------------------------
// Wfe = -0.5*(Wf + Wf^T) as split bf16. d=1024.
// ---------------------------------------------------------------------------
__global__ __launch_bounds__(256)
void symm_split(const float* __restrict__ Wf, short* __restrict__ Fh, short* __restrict__ Fl)
{
    const int i  = blockIdx.x;
    const int j0 = threadIdx.x * 4;
    const float4 rv = *(const float4*)&Wf[(size_t)i * 1024 + j0];
    const float c0 = Wf[(size_t)(j0 + 0) * 1024 + i];
    const float c1 = Wf[(size_t)(j0 + 1) * 1024 + i];
    const float c2 = Wf[(size_t)(j0 + 2) * 1024 + i];
    const float c3 = Wf[(size_t)(j0 + 3) * 1024 + i];
    const float v[4] = {-0.5f * (rv.x + c0), -0.5f * (rv.y + c1),
                        -0.5f * (rv.z + c2), -0.5f * (rv.w + c3)};
    short4v h, l;
#pragma unroll
    for (int k = 0; k < 4; ++k) {
        const short hh = f2bf(v[k]);
        h[k] = hh;
        l[k] = f2bf(v[k] - bf2f(hh));
    }
    *(short4v*)&Fh[(size_t)i * 1024 + j0] = h;
    *(short4v*)&Fl[(size_t)i * 1024 + j0] = l;
}

// ---------------------------------------------------------------------------
extern "C" void kernel_launch(void* const* d_in, const int* in_sizes, int n_in,
                              void* d_out, int out_size, void* d_ws, size_t ws_size,
                              hipStream_t stream)
{
    const float* Y  = (const float*)d_in[0];   // (4096, 1024)
    const float* W  = (const float*)d_in[1];   // (1024, 1024)
    const float* Wf = (const float*)d_in[2];   // (1024, 1024)
    const float* Bb = (const float*)d_in[3];   // (1, 1024)
    float* out = (float*)d_out;

    const int n = 4096, d = 1024;

    // ws layout (104.86 MB total == round-1 proven footprint):
    char* w = (char*)d_ws;
    short* Ythi = (short*)w; w += (size_t)d * n * 2;   // 8.39 MB
    short* Ytlo = (short*)w; w += (size_t)d * n * 2;
    short* Wfeh = (short*)w; w += (size_t)d * d * 2;   // 2.10 MB
    short* Wfel = (short*)w; w += (size_t)d * d * 2;
    short* YWth = (short*)w; w += (size_t)n * d * 2;   // 8.39 MB (reused as Zhi)
    short* YWtl = (short*)w; w += (size_t)n * d * 2;   //          (reused as Zlo)
    short* Shi  = (short*)w; w += (size_t)n * n * 2;   // 33.55 MB (in-place A)
    short* Slo  = (short*)w; w += (size_t)n * n * 2;
    short* Zhi = YWth; short* Zlo = YWtl;

    transpose_split<<<dim3(16, 64), 256, 0, stream>>>(Y, Ythi, Ytlo);
    symm_split<<<dim3(1024), 256, 0, stream>>>(Wf, Wfeh, Wfel);

    // 1) YWt = Y @ W^T  (fp32 inputs, split-bf16 staged in-kernel)
    mfma_gemm<true, false><<<dim3(8, 32), 256, 0, stream>>>(
        Y, nullptr, W, nullptr, nullptr, YWth, YWtl, n, d, d);

    // 2) S = YWt @ YWt^T  -> split bf16 logits
    mfma_gemm<false, false><<<dim3(32, 32), 256, 0, stream>>>(
        YWth, YWtl, YWth, YWtl, nullptr, Shi, Slo, n, n, d);

    // 3) A = softmax(S), in place on the split pair
    softmax_split_inplace<<<dim3(n), 256, 0, stream>>>(Shi, Slo);

    // 4) Z = A @ Y  (B-operand = Yt rows)
    mfma_gemm<false, false><<<dim3(8, 32), 256, 0, stream>>>(
        Shi, Slo, Ythi, Ytlo, nullptr, Zhi, Zlo, n, d, n);

    // 5) out = relu(Z @ Wfe + B)  (Wfe symmetric -> its rows are B^T form)
    mfma_gemm<false, true><<<dim3(8, 32), 256, 0, stream>>>(
        Zhi, Zlo, Wfeh, Wfel, Bb, out, nullptr, n, d, d);
}

// Round 3
// 306.352 us; speedup vs baseline: 4.1054x; 1.5663x over previous
//
#include <hip/hip_runtime.h>
#include <cstdint>
#include <cmath>

// ---------------------------------------------------------------------------
// out = relu((softmax((Y W^T)(Y W^T)^T) @ Y) @ (-0.5(Wf+Wf^T)) + B)
// n=4096, d=1024, fp32 in/out.
// R3: precision-tiered split-bf16 MFMA:
//   - GEMM1 (Y@W^T)  : 3-product split (feeds logits quadratically)
//   - GEMM2 (S=XX^T) : 3-product split, SYMMETRIC upper-tri grid (528 blocks)
//                      with mirrored epilogue writes
//   - GEMM3 (A@Y)    : pure bf16 1-product (softmax output tolerant)
//   - GEMM4 (Z@Wfe)  : pure bf16 1-product + bias + relu
// All GEMMs: 128x128 tile, double-buffered LDS (64KB), 2-phase prefetch
// (STAGE next tile before compute of current, single vmcnt(0)+barrier/step).
// SPLIT mode BK=32, HI mode BK=64. XOR-swizzled LDS (verified 0 conflicts).
// ---------------------------------------------------------------------------

typedef __attribute__((ext_vector_type(8))) short short8;
typedef __attribute__((ext_vector_type(4))) short short4v;
typedef __attribute__((ext_vector_type(4))) float f32x4;

__device__ __forceinline__ short f2bf(float x) {            // RNE fp32 -> bf16
    unsigned u = __builtin_bit_cast(unsigned, x);
    u += 0x7fffu + ((u >> 16) & 1u);
    return (short)(u >> 16);
}
__device__ __forceinline__ float bf2f(short s) {
    unsigned u = ((unsigned)(unsigned short)s) << 16;
    return __builtin_bit_cast(float, u);
}

typedef const __attribute__((address_space(1))) void* gas1_t;
typedef __attribute__((address_space(3))) void* las3_t;
__device__ __forceinline__ void cp16(const void* g, void* l) {
    __builtin_amdgcn_global_load_lds((gas1_t)(uintptr_t)g, (las3_t)(uintptr_t)l, 16, 0, 0);
}

// ---------------------------------------------------------------------------
// OUTMODE: 0 = split bf16 (hi+lo), 1 = hi bf16 only, 2 = fp32 + bias + relu
// ---------------------------------------------------------------------------
template<bool SPLIT, int OUTMODE, bool SYMM>
__global__ __launch_bounds__(256)
void mfma_gemm(const short* __restrict__ Ah, const short* __restrict__ Al,
               const short* __restrict__ Bh, const short* __restrict__ Bl,
               const float* __restrict__ bias, void* Co_, void* Cl_,
               int M, int N, int K)
{
    constexpr int BK = SPLIT ? 32 : 64;
    constexpr int NT = SPLIT ? 4 : 2;          // tiles: (Ah,Al,Bh,Bl) or (Ah,Bh)
    constexpr int TS = 128 * BK;               // shorts per tile
    __shared__ short lds[2][NT][TS];           // 64 KB both modes

    const int tid  = threadIdx.x;
    const int lane = tid & 63;
    const int wave = tid >> 6;
    const int wr   = wave >> 1, wc = wave & 1;

    int bm, bn, bi = 0, bj = 0;
    if (SYMM) {
        const int NB = N >> 7;                 // 32 block-rows
        int lin = blockIdx.x;
        const int nwg = gridDim.x;             // 528 = 8*66
        if ((nwg & 7) == 0) lin = (lin & 7) * (nwg >> 3) + (lin >> 3);
        const float ff = (float)(2 * NB + 1);
        int i = (int)((ff - sqrtf(ff * ff - 8.0f * (float)lin)) * 0.5f);
        while ((i + 1) * (2 * NB - i) / 2 <= lin) ++i;
        while (i * (2 * NB - i + 1) / 2 > lin) --i;
        bi = i;
        bj = i + (lin - i * (2 * NB - i + 1) / 2);
        bm = bi << 7; bn = bj << 7;
    } else {
        const int gx  = gridDim.x;
        const int nwg = gx * gridDim.y;
        int lin = blockIdx.y * gx + blockIdx.x;
        if ((nwg & 7) == 0) { const int cpx = nwg >> 3; lin = (lin & 7) * cpx + (lin >> 3); }
        bm = (lin / gx) << 7;
        bn = (lin % gx) << 7;
    }

    f32x4 acc[4][4];
#pragma unroll
    for (int i = 0; i < 4; ++i)
#pragma unroll
        for (int j = 0; j < 4; ++j)
#pragma unroll
            for (int q = 0; q < 4; ++q) acc[i][j][q] = 0.f;

    // --- staging source pointers ---
    const short *pA0, *pA1, *pA2, *pA3, *pB0, *pB1, *pB2, *pB3;
    if constexpr (SPLIT) {
        const int srow = tid >> 2;                       // 0..63
        const int csw  = (tid & 3) ^ ((tid >> 3) & 3);   // logical chunk (4/row)
        const size_t oA = (size_t)(bm + srow) * K + csw * 8;
        const size_t oB = (size_t)(bn + srow) * K + csw * 8;
        pA0 = Ah + oA; pA1 = Ah + oA + (size_t)64 * K;
        pA2 = Al + oA; pA3 = Al + oA + (size_t)64 * K;
        pB0 = Bh + oB; pB1 = Bh + oB + (size_t)64 * K;
        pB2 = Bl + oB; pB3 = Bl + oB + (size_t)64 * K;
    } else {
        const int srow = tid >> 3;                       // 0..31
        const int lch  = (tid & 7) ^ (srow & 7);         // logical chunk (8/row)
        const size_t oA = (size_t)(bm + srow) * K + lch * 8;
        const size_t oB = (size_t)(bn + srow) * K + lch * 8;
        pA0 = Ah + oA; pA1 = pA0 + (size_t)32 * K;
        pA2 = pA0 + (size_t)64 * K; pA3 = pA0 + (size_t)96 * K;
        pB0 = Bh + oB; pB1 = pB0 + (size_t)32 * K;
        pB2 = pB0 + (size_t)64 * K; pB3 = pB0 + (size_t)96 * K;
    }

    auto stage = [&](int buf, int t) {
        short* db = &lds[buf][0][0] + tid * 8;           // lane*16B within tile
        const int ko = t * BK;
        if constexpr (SPLIT) {
            cp16(pA0 + ko, db);                cp16(pA1 + ko, db + 2048);
            cp16(pA2 + ko, db + 4096);         cp16(pA3 + ko, db + 4096 + 2048);
            cp16(pB0 + ko, db + 8192);         cp16(pB1 + ko, db + 8192 + 2048);
            cp16(pB2 + ko, db + 12288);        cp16(pB3 + ko, db + 12288 + 2048);
        } else {
            cp16(pA0 + ko, db);         cp16(pA1 + ko, db + 2048);
            cp16(pA2 + ko, db + 4096);  cp16(pA3 + ko, db + 6144);
            cp16(pB0 + ko, db + 8192);  cp16(pB1 + ko, db + 8192 + 2048);
            cp16(pB2 + ko, db + 8192 + 4096);  cp16(pB3 + ko, db + 8192 + 6144);
        }
    };

    // --- fragment base offsets (swizzled; R2-verified pattern for SPLIT) ---
    int aoff, boff;
    if constexpr (SPLIT) {
        const int fsw = ((lane >> 4) ^ ((lane >> 1) & 3)) * 8;
        aoff = (wr * 64 + (lane & 15)) * 32 + fsw;
        boff = (wc * 64 + (lane & 15)) * 32 + fsw;
    } else {
        aoff = (wr * 64 + (lane & 15)) * 64;
        boff = (wc * 64 + (lane & 15)) * 64;
    }

    const int nt = K / BK;
    int cur = 0;

    stage(0, 0);
    asm volatile("s_waitcnt vmcnt(0)" ::: "memory");
    __syncthreads();

    for (int t = 0; t < nt; ++t) {
        if (t + 1 < nt) stage(cur ^ 1, t + 1);           // prefetch next tile
        const short* base = &lds[cur][0][0];
        if constexpr (SPLIT) {
            short8 fah[4], fal[4], fbh[4], fbl[4];
#pragma unroll
            for (int i = 0; i < 4; ++i) {
                fah[i] = *(const short8*)(base + aoff + i * 512);
                fal[i] = *(const short8*)(base + 4096 + aoff + i * 512);
            }
#pragma unroll
            for (int j = 0; j < 4; ++j) {
                fbh[j] = *(const short8*)(base + 8192 + boff + j * 512);
                fbl[j] = *(const short8*)(base + 12288 + boff + j * 512);
            }
#pragma unroll
            for (int i = 0; i < 4; ++i)
#pragma unroll
                for (int j = 0; j < 4; ++j) {
                    acc[i][j] = __builtin_amdgcn_mfma_f32_16x16x32_bf16(fah[i], fbh[j], acc[i][j], 0, 0, 0);
                    acc[i][j] = __builtin_amdgcn_mfma_f32_16x16x32_bf16(fah[i], fbl[j], acc[i][j], 0, 0, 0);
                    acc[i][j] = __builtin_amdgcn_mfma_f32_16x16x32_bf16(fal[i], fbh[j], acc[i][j], 0, 0, 0);
                }
        } else {
#pragma unroll
            for (int ks = 0; ks < 2; ++ks) {
                const int sw = ((ks * 4 + (lane >> 4)) ^ (lane & 7)) * 8;
                short8 fa[4], fb[4];
#pragma unroll
                for (int i = 0; i < 4; ++i)
                    fa[i] = *(const short8*)(base + aoff + sw + i * 1024);
#pragma unroll
                for (int j = 0; j < 4; ++j)
                    fb[j] = *(const short8*)(base + 8192 + boff + sw + j * 1024);
#pragma unroll
                for (int i = 0; i < 4; ++i)
#pragma unroll
                    for (int j = 0; j < 4; ++j)
                        acc[i][j] = __builtin_amdgcn_mfma_f32_16x16x32_bf16(fa[i], fb[j], acc[i][j], 0, 0, 0);
            }
        }
        asm volatile("s_waitcnt vmcnt(0)" ::: "memory");  // prefetched tile landed
        __syncthreads();
        cur ^= 1;
    }

    // --- epilogue: C/D layout col = lane&15, row = (lane>>4)*4 + q ---
    const int crow0 = bm + wr * 64 + ((lane >> 4) << 2);
    const int ccol0 = bn + wc * 64 + (lane & 15);
    if constexpr (OUTMODE == 2) {
        float* C = (float*)Co_;
#pragma unroll
        for (int j = 0; j < 4; ++j) {
            const int c = ccol0 + j * 16;
            const float bv = bias[c];
#pragma unroll
            for (int i = 0; i < 4; ++i)
#pragma unroll
                for (int q = 0; q < 4; ++q) {
                    const int r = crow0 + i * 16 + q;
                    C[(size_t)r * N + c] = fmaxf(acc[i][j][q] + bv, 0.f);
                }
        }
    } else if constexpr (OUTMODE == 1) {
        short* Ch = (short*)Co_;
#pragma unroll
        for (int j = 0; j < 4; ++j) {
            const int c = ccol0 + j * 16;
#pragma unroll
            for (int i = 0; i < 4; ++i)
#pragma unroll
                for (int q = 0; q < 4; ++q) {
                    const int r = crow0 + i * 16 + q;
                    Ch[(size_t)r * N + c] = f2bf(acc[i][j][q]);
                }
        }
    } else {
        short* Ch = (short*)Co_;
        short* Cl = (short*)Cl_;
        const bool mirror = SYMM && (bi != bj);
#pragma unroll
        for (int j = 0; j < 4; ++j) {
            const int c = ccol0 + j * 16;
#pragma unroll
            for (int i = 0; i < 4; ++i)
#pragma unroll
                for (int q = 0; q < 4; ++q) {
                    const int r = crow0 + i * 16 + q;
                    const float v = acc[i][j][q];
                    const short hh = f2bf(v);
                    const short ll = f2bf(v - bf2f(hh));
                    Ch[(size_t)r * N + c] = hh;
                    Cl[(size_t)r * N + c] = ll;
                    if (mirror) {
                        Ch[(size_t)c * N + r] = hh;
                        Cl[(size_t)c * N + r] = ll;
                    }
                }
        }
    }
}

// ---------------------------------------------------------------------------
// Row softmax over split logits; writes PROBABILITIES as hi-bf16 only (into Shi).
// ---------------------------------------------------------------------------
__global__ __launch_bounds__(256)
void softmax_hi(short* __restrict__ Shi, const short* __restrict__ Slo)
{
    const int row = blockIdx.x;
    short8* ph = (short8*)(Shi + (size_t)row * 4096);
    const short8* pl = (const short8*)(Slo + (size_t)row * 4096);
    const int t = threadIdx.x;

    short8 h0 = ph[t], h1 = ph[t + 256];
    short8 l0 = pl[t], l1 = pl[t + 256];
    float x[16];
#pragma unroll
    for (int j = 0; j < 8; ++j) {
        x[j]     = bf2f(h0[j]) + bf2f(l0[j]);
        x[8 + j] = bf2f(h1[j]) + bf2f(l1[j]);
    }
    float mx = x[0];
#pragma unroll
    for (int j = 1; j < 16; ++j) mx = fmaxf(mx, x[j]);
#pragma unroll
    for (int off = 32; off > 0; off >>= 1) mx = fmaxf(mx, __shfl_xor(mx, off));

    __shared__ float rm[4], rs[4];
    const int wv = t >> 6, ln = t & 63;
    if (ln == 0) rm[wv] = mx;
    __syncthreads();
    mx = fmaxf(fmaxf(rm[0], rm[1]), fmaxf(rm[2], rm[3]));

    float s = 0.f;
#pragma unroll
    for (int j = 0; j < 16; ++j) { x[j] = __expf(x[j] - mx); s += x[j]; }
#pragma unroll
    for (int off = 32; off > 0; off >>= 1) s += __shfl_xor(s, off);
    if (ln == 0) rs[wv] = s;
    __syncthreads();
    s = rs[0] + rs[1] + rs[2] + rs[3];

    const float inv = 1.f / s;
    short8 o0, o1;
#pragma unroll
    for (int j = 0; j < 8; ++j) {
        o0[j] = f2bf(x[j] * inv);
        o1[j] = f2bf(x[8 + j] * inv);
    }
    ph[t] = o0; ph[t + 256] = o1;
}

// ---------------------------------------------------------------------------
// Y (4096x1024 f32) -> Yhi/Ylo (row-major split) + Ythi (transposed hi bf16)
// ---------------------------------------------------------------------------
__global__ __launch_bounds__(256)
void split_y(const float* __restrict__ Y, short* __restrict__ Yhi,
             short* __restrict__ Ylo, short* __restrict__ Yt)
{
    __shared__ float tb[64][65];
    const int rb = blockIdx.y * 64, cb = blockIdx.x * 64;
    const int t = threadIdx.x;
    const int r = t >> 4, c4 = (t & 15) * 4;
#pragma unroll
    for (int it = 0; it < 4; ++it) {
        const int row = rb + r + it * 16;
        const float4 v = *(const float4*)&Y[(size_t)row * 1024 + cb + c4];
        const float f[4] = {v.x, v.y, v.z, v.w};
        short4v h, l;
#pragma unroll
        for (int k = 0; k < 4; ++k) {
            const short hh = f2bf(f[k]);
            h[k] = hh;
            l[k] = f2bf(f[k] - bf2f(hh));
        }
        *(short4v*)&Yhi[(size_t)row * 1024 + cb + c4] = h;
        *(short4v*)&Ylo[(size_t)row * 1024 + cb + c4] = l;
        tb[r + it * 16][c4 + 0] = v.x; tb[r + it * 16][c4 + 1] = v.y;
        tb[r + it * 16][c4 + 2] = v.z; tb[r + it * 16][c4 + 3] = v.w;
    }
    __syncthreads();
    const int orow = t >> 2, oc0 = (t & 3) * 16;
    short8 h8[2];
#pragma unroll
    for (int g = 0; g < 2; ++g)
#pragma unroll
        for (int j = 0; j < 8; ++j)
            h8[g][j] = f2bf(tb[oc0 + g * 8 + j][orow]);
    const size_t ob = (size_t)(cb + orow) * 4096 + rb + oc0;
    *(short8*)&Yt[ob] = h8[0];
    *(short8*)&Yt[ob + 8] = h8[1];
}

// W (1024x1024 f32) -> Whi/Wlo
__global__ __launch_bounds__(256)
void split_w(const float* __restrict__ Wm, short* __restrict__ Wh, short* __restrict__ Wl)
{
    const size_t idx = ((size_t)blockIdx.x * 256 + threadIdx.x) * 4;
    const float4 v = *(const float4*)&Wm[idx];
    const float f[4] = {v.x, v.y, v.z, v.w};
    short4v h, l;
#pragma unroll
    for (int k = 0; k < 4; ++k) {
        const short hh = f2bf(f[k]);
        h[k] = hh;
        l[k] = f2bf(f[k] - bf2f(hh));
    }
    *(short4v*)&Wh[idx] = h;
    *(short4v*)&Wl[idx] = l;
}

// Wfeh = bf16(-0.5*(Wf + Wf^T))
__global__ __launch_bounds__(256)
void symm_hi(const float* __restrict__ Wf, short* __restrict__ Fh)
{
    const int i  = blockIdx.x;
    const int j0 = threadIdx.x * 4;
    const float4 rv = *(const float4*)&Wf[(size_t)i * 1024 + j0];
    const float c0 = Wf[(size_t)(j0 + 0) * 1024 + i];
    const float c1 = Wf[(size_t)(j0 + 1) * 1024 + i];
    const float c2 = Wf[(size_t)(j0 + 2) * 1024 + i];
    const float c3 = Wf[(size_t)(j0 + 3) * 1024 + i];
    short4v h;
    h[0] = f2bf(-0.5f * (rv.x + c0));
    h[1] = f2bf(-0.5f * (rv.y + c1));
    h[2] = f2bf(-0.5f * (rv.z + c2));
    h[3] = f2bf(-0.5f * (rv.w + c3));
    *(short4v*)&Fh[(size_t)i * 1024 + j0] = h;
}

// ---------------------------------------------------------------------------
extern "C" void kernel_launch(void* const* d_in, const int* in_sizes, int n_in,
                              void* d_out, int out_size, void* d_ws, size_t ws_size,
                              hipStream_t stream)
{
    const float* Y  = (const float*)d_in[0];   // (4096, 1024)
    const float* W  = (const float*)d_in[1];   // (1024, 1024)
    const float* Wf = (const float*)d_in[2];   // (1024, 1024)
    const float* Bb = (const float*)d_in[3];   // (1, 1024)
    float* out = (float*)d_out;

    const int n = 4096, d = 1024;

    // ws layout, 94.4 MB total (<= R2's proven 104.9 MB):
    char* w = (char*)d_ws;
    short* Ythi = (short*)w; w += (size_t)d * n * 2;   //  8.39 MB
    short* Wfeh = (short*)w; w += (size_t)d * d * 2;   //  2.10 MB
    short* YWth = (short*)w; w += (size_t)n * d * 2;   //  8.39 MB (reused as Zhi)
    short* YWtl = (short*)w; w += (size_t)n * d * 2;   //  8.39 MB
    short* Shi  = (short*)w; w += (size_t)n * n * 2;   // 33.55 MB
    short* Slo  = (short*)w; w += (size_t)n * n * 2;   // 33.55 MB
    // transient split inputs aliased into the Shi region (dead before S written):
    short* Yhi = Shi;
    short* Ylo = Yhi + (size_t)n * d;
    short* Whi = Ylo + (size_t)n * d;
    short* Wlo = Whi + (size_t)d * d;
    short* Zhi = YWth;                                  // YWt dead after GEMM2

    split_y<<<dim3(16, 64), 256, 0, stream>>>(Y, Yhi, Ylo, Ythi);
    split_w<<<dim3(1024), 256, 0, stream>>>(W, Whi, Wlo);
    symm_hi<<<dim3(1024), 256, 0, stream>>>(Wf, Wfeh);

    // 1) YWt = Y @ W^T (split 3-product)
    mfma_gemm<true, 0, false><<<dim3(8, 32), 256, 0, stream>>>(
        Yhi, Ylo, Whi, Wlo, nullptr, YWth, YWtl, n, d, d);

    // 2) S = YWt @ YWt^T (split 3-product, symmetric upper-tri + mirror)
    mfma_gemm<true, 0, true><<<dim3(528), 256, 0, stream>>>(
        YWth, YWtl, YWth, YWtl, nullptr, Shi, Slo, n, n, d);

    // 3) A = softmax(S): probabilities as hi-bf16 into Shi
    softmax_hi<<<dim3(n), 256, 0, stream>>>(Shi, Slo);

    // 4) Z = A @ Y (pure bf16 1-product)
    mfma_gemm<false, 1, false><<<dim3(8, 32), 256, 0, stream>>>(
        Shi, nullptr, Ythi, nullptr, nullptr, Zhi, nullptr, n, d, n);

    // 5) out = relu(Z @ Wfe + B) (pure bf16 1-product)
    mfma_gemm<false, 2, false><<<dim3(8, 32), 256, 0, stream>>>(
        Zhi, nullptr, Wfeh, nullptr, Bb, out, nullptr, n, d, d);
}

// Round 4
// 306.181 us; speedup vs baseline: 4.1077x; 1.0006x over previous
//
#include <hip/hip_runtime.h>
#include <cstdint>
#include <cmath>

// ---------------------------------------------------------------------------
// out = relu((softmax((Y W^T)(Y W^T)^T) @ Y) @ (-0.5(Wf+Wf^T)) + B)
// n=4096, d=1024, fp32 in/out.
// R4: 8-wave (512-thread) 128x128 tiles -> 2 waves/SIMD even at 1 block/CU
// (4/SIMD for GEMM2's 528-block tri grid), so per-step drains overlap across
// waves. Precision tiering and verified XOR swizzles unchanged from R3:
//   GEMM1 (Y@W^T)  split 3-product | GEMM2 (S=XX^T) split, upper-tri+mirror
//   GEMM3 (A@Y)    hi 1-product    | GEMM4 (Z@Wfe)  hi 1-product +bias+relu
// ---------------------------------------------------------------------------

typedef __attribute__((ext_vector_type(8))) short short8;
typedef __attribute__((ext_vector_type(4))) short short4v;
typedef __attribute__((ext_vector_type(4))) float f32x4;

__device__ __forceinline__ short f2bf(float x) {            // RNE fp32 -> bf16
    unsigned u = __builtin_bit_cast(unsigned, x);
    u += 0x7fffu + ((u >> 16) & 1u);
    return (short)(u >> 16);
}
__device__ __forceinline__ float bf2f(short s) {
    unsigned u = ((unsigned)(unsigned short)s) << 16;
    return __builtin_bit_cast(float, u);
}

typedef const __attribute__((address_space(1))) void* gas1_t;
typedef __attribute__((address_space(3))) void* las3_t;
__device__ __forceinline__ void cp16(const void* g, void* l) {
    __builtin_amdgcn_global_load_lds((gas1_t)(uintptr_t)g, (las3_t)(uintptr_t)l, 16, 0, 0);
}

// ---------------------------------------------------------------------------
// 512 threads = 8 waves, wave grid 2(M,64 rows) x 4(N,32 cols), acc[4][2].
// SPLIT: BK=32, LDS buf = 4 planes (Ah,Al,Bh,Bl) x [128][32]sh = 32KB
// HI   : BK=64, LDS buf = 2 planes (A,B)         x [128][64]sh = 32KB
// Double-buffered (64KB), 2-phase prefetch, single vmcnt(0)+barrier per step.
// OUTMODE: 0 = split bf16 (hi+lo, SYMM mirror opt), 1 = hi bf16, 2 = f32+bias+relu
// ---------------------------------------------------------------------------
template<bool SPLIT, int OUTMODE, bool SYMM>
__global__ __launch_bounds__(512, 4)
void mfma_gemm(const short* __restrict__ Ah, const short* __restrict__ Al,
               const short* __restrict__ Bh, const short* __restrict__ Bl,
               const float* __restrict__ bias, void* Co_, void* Cl_,
               int M, int N, int K)
{
    constexpr int BK = SPLIT ? 32 : 64;
    __shared__ short lds[2][16384];            // 64 KB

    const int tid  = threadIdx.x;
    const int lane = tid & 63;
    const int wave = tid >> 6;
    const int wr   = wave >> 2;                // 0..1 : 64-row half
    const int wc   = wave & 3;                 // 0..3 : 32-col quarter

    int bm, bn, bi = 0, bj = 0;
    if (SYMM) {
        const int NB = N >> 7;
        int lin = blockIdx.x;
        const int nwg = gridDim.x;             // 528 = 8*66
        if ((nwg & 7) == 0) lin = (lin & 7) * (nwg >> 3) + (lin >> 3);
        const float ff = (float)(2 * NB + 1);
        int i = (int)((ff - sqrtf(ff * ff - 8.0f * (float)lin)) * 0.5f);
        while ((i + 1) * (2 * NB - i) / 2 <= lin) ++i;
        while (i * (2 * NB - i + 1) / 2 > lin) --i;
        bi = i;
        bj = i + (lin - i * (2 * NB - i + 1) / 2);
        bm = bi << 7; bn = bj << 7;
    } else {
        const int gx  = gridDim.x;
        const int nwg = gx * gridDim.y;
        int lin = blockIdx.y * gx + blockIdx.x;
        if ((nwg & 7) == 0) { const int cpx = nwg >> 3; lin = (lin & 7) * cpx + (lin >> 3); }
        bm = (lin / gx) << 7;
        bn = (lin % gx) << 7;
    }

    f32x4 acc[4][2];
#pragma unroll
    for (int m = 0; m < 4; ++m)
#pragma unroll
        for (int n = 0; n < 2; ++n)
#pragma unroll
            for (int q = 0; q < 4; ++q) acc[m][n][q] = 0.f;

    // --- staging source pointers (4 cp16 per thread per buffer fill) ---
    const short *pA0, *pA1, *pB0, *pB1;
    if constexpr (SPLIT) {
        const int row = tid >> 2;                        // 0..127
        const int csw = (tid & 3) ^ ((tid >> 3) & 3);    // logical chunk of 4
        const size_t oA = (size_t)(bm + row) * K + csw * 8;
        const size_t oB = (size_t)(bn + row) * K + csw * 8;
        pA0 = Ah + oA; pA1 = Al + oA;                    // planes 0,1
        pB0 = Bh + oB; pB1 = Bl + oB;                    // planes 2,3
    } else {
        const int row = tid >> 3;                        // 0..63
        const int lch = (tid & 7) ^ ((tid >> 3) & 7);    // logical chunk of 8
        const size_t oA = (size_t)(bm + row) * K + lch * 8;
        const size_t oB = (size_t)(bn + row) * K + lch * 8;
        pA0 = Ah + oA; pA1 = pA0 + (size_t)64 * K;       // A rows 0..63 / 64..127
        pB0 = Bh + oB; pB1 = pB0 + (size_t)64 * K;       // B rows
    }

    auto stage = [&](int buf, int t) {
        short* db = &lds[buf][0] + tid * 8;              // lane*16B, wave-uniform base
        const int ko = t * BK;
        cp16(pA0 + ko, db);
        cp16(pA1 + ko, db + 4096);
        cp16(pB0 + ko, db + 8192);
        cp16(pB1 + ko, db + 12288);
    };

    // --- fragment base offsets (verified swizzles) ---
    int aoff, boff;
    if constexpr (SPLIT) {
        const int swz = ((lane >> 4) ^ ((lane >> 1) & 3)) * 8;
        aoff = (wr * 64 + (lane & 15)) * 32 + swz;
        boff = (wc * 32 + (lane & 15)) * 32 + swz;
    } else {
        aoff = (wr * 64 + (lane & 15)) * 64;
        boff = (wc * 32 + (lane & 15)) * 64;
    }

    const int nt = K / BK;
    int cur = 0;

    stage(0, 0);
    asm volatile("s_waitcnt vmcnt(0)" ::: "memory");
    __syncthreads();

    for (int t = 0; t < nt; ++t) {
        if (t + 1 < nt) stage(cur ^ 1, t + 1);           // prefetch next K-step
        const short* base = &lds[cur][0];
        if constexpr (SPLIT) {
            short8 fah[4], fal[4];
#pragma unroll
            for (int m = 0; m < 4; ++m) {
                fah[m] = *(const short8*)(base + aoff + m * 512);
                fal[m] = *(const short8*)(base + 4096 + aoff + m * 512);
            }
#pragma unroll
            for (int n = 0; n < 2; ++n) {
                const short8 fbh = *(const short8*)(base + 8192 + boff + n * 512);
                const short8 fbl = *(const short8*)(base + 12288 + boff + n * 512);
#pragma unroll
                for (int m = 0; m < 4; ++m) {
                    acc[m][n] = __builtin_amdgcn_mfma_f32_16x16x32_bf16(fah[m], fbh, acc[m][n], 0, 0, 0);
                    acc[m][n] = __builtin_amdgcn_mfma_f32_16x16x32_bf16(fah[m], fbl, acc[m][n], 0, 0, 0);
                    acc[m][n] = __builtin_amdgcn_mfma_f32_16x16x32_bf16(fal[m], fbh, acc[m][n], 0, 0, 0);
                }
            }
        } else {
#pragma unroll
            for (int ks = 0; ks < 2; ++ks) {
                const int sw = ((ks * 4 + (lane >> 4)) ^ (lane & 7)) * 8;
                short8 fa[4], fb[2];
#pragma unroll
                for (int m = 0; m < 4; ++m)
                    fa[m] = *(const short8*)(base + aoff + sw + m * 1024);
#pragma unroll
                for (int n = 0; n < 2; ++n)
                    fb[n] = *(const short8*)(base + 8192 + boff + sw + n * 1024);
#pragma unroll
                for (int m = 0; m < 4; ++m)
#pragma unroll
                    for (int n = 0; n < 2; ++n)
                        acc[m][n] = __builtin_amdgcn_mfma_f32_16x16x32_bf16(fa[m], fb[n], acc[m][n], 0, 0, 0);
            }
        }
        asm volatile("s_waitcnt vmcnt(0)" ::: "memory");  // prefetched tile landed
        __syncthreads();
        cur ^= 1;
    }

    // --- epilogue: C/D layout col = lane&15, row = (lane>>4)*4 + q ---
    const int crow0 = bm + wr * 64 + ((lane >> 4) << 2);
    const int ccol0 = bn + wc * 32 + (lane & 15);
    if constexpr (OUTMODE == 2) {
        float* C = (float*)Co_;
#pragma unroll
        for (int n = 0; n < 2; ++n) {
            const int c = ccol0 + n * 16;
            const float bv = bias[c];
#pragma unroll
            for (int m = 0; m < 4; ++m)
#pragma unroll
                for (int q = 0; q < 4; ++q) {
                    const int r = crow0 + m * 16 + q;
                    C[(size_t)r * N + c] = fmaxf(acc[m][n][q] + bv, 0.f);
                }
        }
    } else if constexpr (OUTMODE == 1) {
        short* Ch = (short*)Co_;
#pragma unroll
        for (int n = 0; n < 2; ++n) {
            const int c = ccol0 + n * 16;
#pragma unroll
            for (int m = 0; m < 4; ++m)
#pragma unroll
                for (int q = 0; q < 4; ++q) {
                    const int r = crow0 + m * 16 + q;
                    Ch[(size_t)r * N + c] = f2bf(acc[m][n][q]);
                }
        }
    } else {
        short* Ch = (short*)Co_;
        short* Cl = (short*)Cl_;
        const bool mirror = SYMM && (bi != bj);
#pragma unroll
        for (int n = 0; n < 2; ++n) {
            const int c = ccol0 + n * 16;
#pragma unroll
            for (int m = 0; m < 4; ++m)
#pragma unroll
                for (int q = 0; q < 4; ++q) {
                    const int r = crow0 + m * 16 + q;
                    const float v = acc[m][n][q];
                    const short hh = f2bf(v);
                    const short ll = f2bf(v - bf2f(hh));
                    Ch[(size_t)r * N + c] = hh;
                    Cl[(size_t)r * N + c] = ll;
                    if (mirror) {
                        Ch[(size_t)c * N + r] = hh;
                        Cl[(size_t)c * N + r] = ll;
                    }
                }
        }
    }
}

// ---------------------------------------------------------------------------
// Row softmax over split logits; writes PROBABILITIES as hi-bf16 into Shi.
// ---------------------------------------------------------------------------
__global__ __launch_bounds__(256)
void softmax_hi(short* __restrict__ Shi, const short* __restrict__ Slo)
{
    const int row = blockIdx.x;
    short8* ph = (short8*)(Shi + (size_t)row * 4096);
    const short8* pl = (const short8*)(Slo + (size_t)row * 4096);
    const int t = threadIdx.x;

    short8 h0 = ph[t], h1 = ph[t + 256];
    short8 l0 = pl[t], l1 = pl[t + 256];
    float x[16];
#pragma unroll
    for (int j = 0; j < 8; ++j) {
        x[j]     = bf2f(h0[j]) + bf2f(l0[j]);
        x[8 + j] = bf2f(h1[j]) + bf2f(l1[j]);
    }
    float mx = x[0];
#pragma unroll
    for (int j = 1; j < 16; ++j) mx = fmaxf(mx, x[j]);
#pragma unroll
    for (int off = 32; off > 0; off >>= 1) mx = fmaxf(mx, __shfl_xor(mx, off));

    __shared__ float rm[4], rs[4];
    const int wv = t >> 6, ln = t & 63;
    if (ln == 0) rm[wv] = mx;
    __syncthreads();
    mx = fmaxf(fmaxf(rm[0], rm[1]), fmaxf(rm[2], rm[3]));

    float s = 0.f;
#pragma unroll
    for (int j = 0; j < 16; ++j) { x[j] = __expf(x[j] - mx); s += x[j]; }
#pragma unroll
    for (int off = 32; off > 0; off >>= 1) s += __shfl_xor(s, off);
    if (ln == 0) rs[wv] = s;
    __syncthreads();
    s = rs[0] + rs[1] + rs[2] + rs[3];

    const float inv = 1.f / s;
    short8 o0, o1;
#pragma unroll
    for (int j = 0; j < 8; ++j) {
        o0[j] = f2bf(x[j] * inv);
        o1[j] = f2bf(x[8 + j] * inv);
    }
    ph[t] = o0; ph[t + 256] = o1;
}

// ---------------------------------------------------------------------------
// Y (4096x1024 f32) -> Yhi/Ylo (row-major split) + Ythi (transposed hi bf16)
// ---------------------------------------------------------------------------
__global__ __launch_bounds__(256)
void split_y(const float* __restrict__ Y, short* __restrict__ Yhi,
             short* __restrict__ Ylo, short* __restrict__ Yt)
{
    __shared__ float tb[64][65];
    const int rb = blockIdx.y * 64, cb = blockIdx.x * 64;
    const int t = threadIdx.x;
    const int r = t >> 4, c4 = (t & 15) * 4;
#pragma unroll
    for (int it = 0; it < 4; ++it) {
        const int row = rb + r + it * 16;
        const float4 v = *(const float4*)&Y[(size_t)row * 1024 + cb + c4];
        const float f[4] = {v.x, v.y, v.z, v.w};
        short4v h, l;
#pragma unroll
        for (int k = 0; k < 4; ++k) {
            const short hh = f2bf(f[k]);
            h[k] = hh;
            l[k] = f2bf(f[k] - bf2f(hh));
        }
        *(short4v*)&Yhi[(size_t)row * 1024 + cb + c4] = h;
        *(short4v*)&Ylo[(size_t)row * 1024 + cb + c4] = l;
        tb[r + it * 16][c4 + 0] = v.x; tb[r + it * 16][c4 + 1] = v.y;
        tb[r + it * 16][c4 + 2] = v.z; tb[r + it * 16][c4 + 3] = v.w;
    }
    __syncthreads();
    const int orow = t >> 2, oc0 = (t & 3) * 16;
    short8 h8[2];
#pragma unroll
    for (int g = 0; g < 2; ++g)
#pragma unroll
        for (int j = 0; j < 8; ++j)
            h8[g][j] = f2bf(tb[oc0 + g * 8 + j][orow]);
    const size_t ob = (size_t)(cb + orow) * 4096 + rb + oc0;
    *(short8*)&Yt[ob] = h8[0];
    *(short8*)&Yt[ob + 8] = h8[1];
}

// W (1024x1024 f32) -> Whi/Wlo
__global__ __launch_bounds__(256)
void split_w(const float* __restrict__ Wm, short* __restrict__ Wh, short* __restrict__ Wl)
{
    const size_t idx = ((size_t)blockIdx.x * 256 + threadIdx.x) * 4;
    const float4 v = *(const float4*)&Wm[idx];
    const float f[4] = {v.x, v.y, v.z, v.w};
    short4v h, l;
#pragma unroll
    for (int k = 0; k < 4; ++k) {
        const short hh = f2bf(f[k]);
        h[k] = hh;
        l[k] = f2bf(f[k] - bf2f(hh));
    }
    *(short4v*)&Wh[idx] = h;
    *(short4v*)&Wl[idx] = l;
}

// Wfeh = bf16(-0.5*(Wf + Wf^T))
__global__ __launch_bounds__(256)
void symm_hi(const float* __restrict__ Wf, short* __restrict__ Fh)
{
    const int i  = blockIdx.x;
    const int j0 = threadIdx.x * 4;
    const float4 rv = *(const float4*)&Wf[(size_t)i * 1024 + j0];
    const float c0 = Wf[(size_t)(j0 + 0) * 1024 + i];
    const float c1 = Wf[(size_t)(j0 + 1) * 1024 + i];
    const float c2 = Wf[(size_t)(j0 + 2) * 1024 + i];
    const float c3 = Wf[(size_t)(j0 + 3) * 1024 + i];
    short4v h;
    h[0] = f2bf(-0.5f * (rv.x + c0));
    h[1] = f2bf(-0.5f * (rv.y + c1));
    h[2] = f2bf(-0.5f * (rv.z + c2));
    h[3] = f2bf(-0.5f * (rv.w + c3));
    *(short4v*)&Fh[(size_t)i * 1024 + j0] = h;
}

// ---------------------------------------------------------------------------
extern "C" void kernel_launch(void* const* d_in, const int* in_sizes, int n_in,
                              void* d_out, int out_size, void* d_ws, size_t ws_size,
                              hipStream_t stream)
{
    const float* Y  = (const float*)d_in[0];   // (4096, 1024)
    const float* W  = (const float*)d_in[1];   // (1024, 1024)
    const float* Wf = (const float*)d_in[2];   // (1024, 1024)
    const float* Bb = (const float*)d_in[3];   // (1, 1024)
    float* out = (float*)d_out;

    const int n = 4096, d = 1024;

    // ws layout, 94.4 MB (same as R3):
    char* w = (char*)d_ws;
    short* Ythi = (short*)w; w += (size_t)d * n * 2;   //  8.39 MB
    short* Wfeh = (short*)w; w += (size_t)d * d * 2;   //  2.10 MB
    short* YWth = (short*)w; w += (size_t)n * d * 2;   //  8.39 MB (reused as Zhi)
    short* YWtl = (short*)w; w += (size_t)n * d * 2;   //  8.39 MB
    short* Shi  = (short*)w; w += (size_t)n * n * 2;   // 33.55 MB
    short* Slo  = (short*)w; w += (size_t)n * n * 2;   // 33.55 MB
    // transient split inputs aliased into Shi region (dead before S written):
    short* Yhi = Shi;
    short* Ylo = Yhi + (size_t)n * d;
    short* Whi = Ylo + (size_t)n * d;
    short* Wlo = Whi + (size_t)d * d;
    short* Zhi = YWth;                                  // YWt dead after GEMM2

    split_y<<<dim3(16, 64), 256, 0, stream>>>(Y, Yhi, Ylo, Ythi);
    split_w<<<dim3(1024), 256, 0, stream>>>(W, Whi, Wlo);
    symm_hi<<<dim3(1024), 256, 0, stream>>>(Wf, Wfeh);

    // 1) YWt = Y @ W^T (split 3-product)
    mfma_gemm<true, 0, false><<<dim3(8, 32), 512, 0, stream>>>(
        Yhi, Ylo, Whi, Wlo, nullptr, YWth, YWtl, n, d, d);

    // 2) S = YWt @ YWt^T (split 3-product, symmetric upper-tri + mirror)
    mfma_gemm<true, 0, true><<<dim3(528), 512, 0, stream>>>(
        YWth, YWtl, YWth, YWtl, nullptr, Shi, Slo, n, n, d);

    // 3) A = softmax(S): probabilities as hi-bf16 into Shi
    softmax_hi<<<dim3(n), 256, 0, stream>>>(Shi, Slo);

    // 4) Z = A @ Y (pure bf16 1-product)
    mfma_gemm<false, 1, false><<<dim3(8, 32), 512, 0, stream>>>(
        Shi, nullptr, Ythi, nullptr, nullptr, Zhi, nullptr, n, d, n);

    // 5) out = relu(Z @ Wfe + B) (pure bf16 1-product)
    mfma_gemm<false, 2, false><<<dim3(8, 32), 512, 0, stream>>>(
        Zhi, nullptr, Wfeh, nullptr, Bb, out, nullptr, n, d, d);
}

// Round 5
// 300.420 us; speedup vs baseline: 4.1864x; 1.0192x over previous
//
#include <hip/hip_runtime.h>
#include <cstdint>
#include <cmath>

// ---------------------------------------------------------------------------
// out = relu((softmax((Y W^T)(Y W^T)^T) @ Y) @ (-0.5(Wf+Wf^T)) + B)
// n=4096, d=1024, fp32 in/out.
// R5: T4 counted-vmcnt pipeline. 4-deep LDS ring (128 KB), raw s_barrier,
// steady-state s_waitcnt vmcnt(8) so 2 staged K-steps stay in flight ACROSS
// the barrier (no per-step drain). T5 setprio around the MFMA cluster.
// Compute/swizzle/epilogue math bit-identical to R3/R4 (passed twice).
//   GEMM1 (Y@W^T)  split 3-product | GEMM2 (S=XX^T) split, upper-tri+mirror
//   GEMM3 (A@Y)    hi 1-product    | GEMM4 (Z@Wfe)  hi 1-product +bias+relu
// ---------------------------------------------------------------------------

typedef __attribute__((ext_vector_type(8))) short short8;
typedef __attribute__((ext_vector_type(4))) short short4v;
typedef __attribute__((ext_vector_type(4))) float f32x4;

__device__ __forceinline__ short f2bf(float x) {            // RNE fp32 -> bf16
    unsigned u = __builtin_bit_cast(unsigned, x);
    u += 0x7fffu + ((u >> 16) & 1u);
    return (short)(u >> 16);
}
__device__ __forceinline__ float bf2f(short s) {
    unsigned u = ((unsigned)(unsigned short)s) << 16;
    return __builtin_bit_cast(float, u);
}

typedef const __attribute__((address_space(1))) void* gas1_t;
typedef __attribute__((address_space(3))) void* las3_t;
__device__ __forceinline__ void cp16(const void* g, void* l) {
    __builtin_amdgcn_global_load_lds((gas1_t)(uintptr_t)g, (las3_t)(uintptr_t)l, 16, 0, 0);
}

// ---------------------------------------------------------------------------
// 512 threads = 8 waves, wave grid 2(M,64 rows) x 4(N,32 cols), acc[4][2].
// SPLIT: BK=32, buffer planes (Ah,Al,Bh,Bl) x [128][32]sh = 32 KB
// HI   : BK=64, buffer planes (A,B)         x [128][64]sh = 32 KB
// Ring of 4 buffers. Pipeline: stage(0,1,2); per step t:
//   wait vmcnt(8|4|0 tail) ; s_barrier ; sched_barrier ;
//   issue stage(t+3) ; ds_read frags ; setprio(1) MFMA cluster setprio(0)
// OUTMODE: 0 = split bf16 (hi+lo, SYMM mirror), 1 = hi bf16, 2 = f32+bias+relu
// ---------------------------------------------------------------------------
template<bool SPLIT, int OUTMODE, bool SYMM>
__global__ __launch_bounds__(512, 2)
void mfma_gemm(const short* __restrict__ Ah, const short* __restrict__ Al,
               const short* __restrict__ Bh, const short* __restrict__ Bl,
               const float* __restrict__ bias, void* Co_, void* Cl_,
               int M, int N, int K)
{
    constexpr int BK = SPLIT ? 32 : 64;
    __shared__ short lds[4][16384];            // 4 x 32 KB ring = 128 KB

    const int tid  = threadIdx.x;
    const int lane = tid & 63;
    const int wave = tid >> 6;
    const int wr   = wave >> 2;                // 0..1 : 64-row half
    const int wc   = wave & 3;                 // 0..3 : 32-col quarter

    int bm, bn, bi = 0, bj = 0;
    if (SYMM) {
        const int NB = N >> 7;
        int lin = blockIdx.x;
        const int nwg = gridDim.x;             // 528 = 8*66
        if ((nwg & 7) == 0) lin = (lin & 7) * (nwg >> 3) + (lin >> 3);
        const float ff = (float)(2 * NB + 1);
        int i = (int)((ff - sqrtf(ff * ff - 8.0f * (float)lin)) * 0.5f);
        while ((i + 1) * (2 * NB - i) / 2 <= lin) ++i;
        while (i * (2 * NB - i + 1) / 2 > lin) --i;
        bi = i;
        bj = i + (lin - i * (2 * NB - i + 1) / 2);
        bm = bi << 7; bn = bj << 7;
    } else {
        const int gx  = gridDim.x;
        const int nwg = gx * gridDim.y;
        int lin = blockIdx.y * gx + blockIdx.x;
        if ((nwg & 7) == 0) { const int cpx = nwg >> 3; lin = (lin & 7) * cpx + (lin >> 3); }
        bm = (lin / gx) << 7;
        bn = (lin % gx) << 7;
    }

    f32x4 acc[4][2];
#pragma unroll
    for (int m = 0; m < 4; ++m)
#pragma unroll
        for (int n = 0; n < 2; ++n)
#pragma unroll
            for (int q = 0; q < 4; ++q) acc[m][n][q] = 0.f;

    // --- staging source pointers (4 cp16 per thread per buffer fill) ---
    const short *pA0, *pA1, *pB0, *pB1;
    if constexpr (SPLIT) {
        const int row = tid >> 2;                        // 0..127
        const int csw = (tid & 3) ^ ((tid >> 3) & 3);    // logical chunk of 4
        const size_t oA = (size_t)(bm + row) * K + csw * 8;
        const size_t oB = (size_t)(bn + row) * K + csw * 8;
        pA0 = Ah + oA; pA1 = Al + oA;                    // planes 0,1
        pB0 = Bh + oB; pB1 = Bl + oB;                    // planes 2,3
    } else {
        const int row = tid >> 3;                        // 0..63
        const int lch = (tid & 7) ^ ((tid >> 3) & 7);    // logical chunk of 8
        const size_t oA = (size_t)(bm + row) * K + lch * 8;
        const size_t oB = (size_t)(bn + row) * K + lch * 8;
        pA0 = Ah + oA; pA1 = pA0 + (size_t)64 * K;       // A rows 0..63 / 64..127
        pB0 = Bh + oB; pB1 = pB0 + (size_t)64 * K;       // B rows
    }

    auto stage = [&](int t) {
        short* db = &lds[t & 3][0] + tid * 8;            // lane*16B, wave-uniform base
        const int ko = t * BK;
        cp16(pA0 + ko, db);
        cp16(pA1 + ko, db + 4096);
        cp16(pB0 + ko, db + 8192);
        cp16(pB1 + ko, db + 12288);
    };

    // --- fragment base offsets (R3/R4-verified swizzles) ---
    int aoff, boff;
    if constexpr (SPLIT) {
        const int swz = ((lane >> 4) ^ ((lane >> 1) & 3)) * 8;
        aoff = (wr * 64 + (lane & 15)) * 32 + swz;
        boff = (wc * 32 + (lane & 15)) * 32 + swz;
    } else {
        aoff = (wr * 64 + (lane & 15)) * 64;
        boff = (wc * 32 + (lane & 15)) * 64;
    }

    const int nt = K / BK;                     // >= 16 for all our shapes

    stage(0); stage(1); stage(2);              // 12 loads outstanding/thread

    for (int t = 0; t < nt; ++t) {
        // wait until buffer t landed: allow 4*min(2, nt-1-t) still in flight
        if (t < nt - 2) {
            asm volatile("s_waitcnt vmcnt(8)" ::: "memory");
        } else if (t == nt - 2) {
            asm volatile("s_waitcnt vmcnt(4)" ::: "memory");
        } else {
            asm volatile("s_waitcnt vmcnt(0)" ::: "memory");
        }
        __builtin_amdgcn_s_barrier();          // raw: does NOT drain vmcnt
        __builtin_amdgcn_sched_barrier(0);     // pin: nothing hoists above

        if (t + 3 < nt) stage(t + 3);          // overwrites buf[t-1]: safe post-barrier

        const short* base = &lds[t & 3][0];
        if constexpr (SPLIT) {
            short8 fah[4], fal[4], fbh[2], fbl[2];
#pragma unroll
            for (int m = 0; m < 4; ++m) {
                fah[m] = *(const short8*)(base + aoff + m * 512);
                fal[m] = *(const short8*)(base + 4096 + aoff + m * 512);
            }
#pragma unroll
            for (int n = 0; n < 2; ++n) {
                fbh[n] = *(const short8*)(base + 8192 + boff + n * 512);
                fbl[n] = *(const short8*)(base + 12288 + boff + n * 512);
            }
            __builtin_amdgcn_s_setprio(1);
#pragma unroll
            for (int m = 0; m < 4; ++m)
#pragma unroll
                for (int n = 0; n < 2; ++n) {
                    acc[m][n] = __builtin_amdgcn_mfma_f32_16x16x32_bf16(fah[m], fbh[n], acc[m][n], 0, 0, 0);
                    acc[m][n] = __builtin_amdgcn_mfma_f32_16x16x32_bf16(fah[m], fbl[n], acc[m][n], 0, 0, 0);
                    acc[m][n] = __builtin_amdgcn_mfma_f32_16x16x32_bf16(fal[m], fbh[n], acc[m][n], 0, 0, 0);
                }
            __builtin_amdgcn_s_setprio(0);
        } else {
            short8 fa[2][4], fb[2][2];
#pragma unroll
            for (int ks = 0; ks < 2; ++ks) {
                const int sw = ((ks * 4 + (lane >> 4)) ^ (lane & 7)) * 8;
#pragma unroll
                for (int m = 0; m < 4; ++m)
                    fa[ks][m] = *(const short8*)(base + aoff + sw + m * 1024);
#pragma unroll
                for (int n = 0; n < 2; ++n)
                    fb[ks][n] = *(const short8*)(base + 8192 + boff + sw + n * 1024);
            }
            __builtin_amdgcn_s_setprio(1);
#pragma unroll
            for (int ks = 0; ks < 2; ++ks)
#pragma unroll
                for (int m = 0; m < 4; ++m)
#pragma unroll
                    for (int n = 0; n < 2; ++n)
                        acc[m][n] = __builtin_amdgcn_mfma_f32_16x16x32_bf16(fa[ks][m], fb[ks][n], acc[m][n], 0, 0, 0);
            __builtin_amdgcn_s_setprio(0);
        }
    }

    // --- epilogue: C/D layout col = lane&15, row = (lane>>4)*4 + q ---
    const int crow0 = bm + wr * 64 + ((lane >> 4) << 2);
    const int ccol0 = bn + wc * 32 + (lane & 15);
    if constexpr (OUTMODE == 2) {
        float* C = (float*)Co_;
#pragma unroll
        for (int n = 0; n < 2; ++n) {
            const int c = ccol0 + n * 16;
            const float bv = bias[c];
#pragma unroll
            for (int m = 0; m < 4; ++m)
#pragma unroll
                for (int q = 0; q < 4; ++q) {
                    const int r = crow0 + m * 16 + q;
                    C[(size_t)r * N + c] = fmaxf(acc[m][n][q] + bv, 0.f);
                }
        }
    } else if constexpr (OUTMODE == 1) {
        short* Ch = (short*)Co_;
#pragma unroll
        for (int n = 0; n < 2; ++n) {
            const int c = ccol0 + n * 16;
#pragma unroll
            for (int m = 0; m < 4; ++m)
#pragma unroll
                for (int q = 0; q < 4; ++q) {
                    const int r = crow0 + m * 16 + q;
                    Ch[(size_t)r * N + c] = f2bf(acc[m][n][q]);
                }
        }
    } else {
        short* Ch = (short*)Co_;
        short* Cl = (short*)Cl_;
        const bool mirror = SYMM && (bi != bj);
#pragma unroll
        for (int n = 0; n < 2; ++n) {
            const int c = ccol0 + n * 16;
#pragma unroll
            for (int m = 0; m < 4; ++m)
#pragma unroll
                for (int q = 0; q < 4; ++q) {
                    const int r = crow0 + m * 16 + q;
                    const float v = acc[m][n][q];
                    const short hh = f2bf(v);
                    const short ll = f2bf(v - bf2f(hh));
                    Ch[(size_t)r * N + c] = hh;
                    Cl[(size_t)r * N + c] = ll;
                    if (mirror) {
                        Ch[(size_t)c * N + r] = hh;
                        Cl[(size_t)c * N + r] = ll;
                    }
                }
        }
    }
}

// ---------------------------------------------------------------------------
// Row softmax over split logits; writes PROBABILITIES as hi-bf16 into Shi.
// ---------------------------------------------------------------------------
__global__ __launch_bounds__(256)
void softmax_hi(short* __restrict__ Shi, const short* __restrict__ Slo)
{
    const int row = blockIdx.x;
    short8* ph = (short8*)(Shi + (size_t)row * 4096);
    const short8* pl = (const short8*)(Slo + (size_t)row * 4096);
    const int t = threadIdx.x;

    short8 h0 = ph[t], h1 = ph[t + 256];
    short8 l0 = pl[t], l1 = pl[t + 256];
    float x[16];
#pragma unroll
    for (int j = 0; j < 8; ++j) {
        x[j]     = bf2f(h0[j]) + bf2f(l0[j]);
        x[8 + j] = bf2f(h1[j]) + bf2f(l1[j]);
    }
    float mx = x[0];
#pragma unroll
    for (int j = 1; j < 16; ++j) mx = fmaxf(mx, x[j]);
#pragma unroll
    for (int off = 32; off > 0; off >>= 1) mx = fmaxf(mx, __shfl_xor(mx, off));

    __shared__ float rm[4], rs[4];
    const int wv = t >> 6, ln = t & 63;
    if (ln == 0) rm[wv] = mx;
    __syncthreads();
    mx = fmaxf(fmaxf(rm[0], rm[1]), fmaxf(rm[2], rm[3]));

    float s = 0.f;
#pragma unroll
    for (int j = 0; j < 16; ++j) { x[j] = __expf(x[j] - mx); s += x[j]; }
#pragma unroll
    for (int off = 32; off > 0; off >>= 1) s += __shfl_xor(s, off);
    if (ln == 0) rs[wv] = s;
    __syncthreads();
    s = rs[0] + rs[1] + rs[2] + rs[3];

    const float inv = 1.f / s;
    short8 o0, o1;
#pragma unroll
    for (int j = 0; j < 8; ++j) {
        o0[j] = f2bf(x[j] * inv);
        o1[j] = f2bf(x[8 + j] * inv);
    }
    ph[t] = o0; ph[t + 256] = o1;
}

// ---------------------------------------------------------------------------
// Y (4096x1024 f32) -> Yhi/Ylo (row-major split) + Ythi (transposed hi bf16)
// ---------------------------------------------------------------------------
__global__ __launch_bounds__(256)
void split_y(const float* __restrict__ Y, short* __restrict__ Yhi,
             short* __restrict__ Ylo, short* __restrict__ Yt)
{
    __shared__ float tb[64][65];
    const int rb = blockIdx.y * 64, cb = blockIdx.x * 64;
    const int t = threadIdx.x;
    const int r = t >> 4, c4 = (t & 15) * 4;
#pragma unroll
    for (int it = 0; it < 4; ++it) {
        const int row = rb + r + it * 16;
        const float4 v = *(const float4*)&Y[(size_t)row * 1024 + cb + c4];
        const float f[4] = {v.x, v.y, v.z, v.w};
        short4v h, l;
#pragma unroll
        for (int k = 0; k < 4; ++k) {
            const short hh = f2bf(f[k]);
            h[k] = hh;
            l[k] = f2bf(f[k] - bf2f(hh));
        }
        *(short4v*)&Yhi[(size_t)row * 1024 + cb + c4] = h;
        *(short4v*)&Ylo[(size_t)row * 1024 + cb + c4] = l;
        tb[r + it * 16][c4 + 0] = v.x; tb[r + it * 16][c4 + 1] = v.y;
        tb[r + it * 16][c4 + 2] = v.z; tb[r + it * 16][c4 + 3] = v.w;
    }
    __syncthreads();
    const int orow = t >> 2, oc0 = (t & 3) * 16;
    short8 h8[2];
#pragma unroll
    for (int g = 0; g < 2; ++g)
#pragma unroll
        for (int j = 0; j < 8; ++j)
            h8[g][j] = f2bf(tb[oc0 + g * 8 + j][orow]);
    const size_t ob = (size_t)(cb + orow) * 4096 + rb + oc0;
    *(short8*)&Yt[ob] = h8[0];
    *(short8*)&Yt[ob + 8] = h8[1];
}

// W (1024x1024 f32) -> Whi/Wlo
__global__ __launch_bounds__(256)
void split_w(const float* __restrict__ Wm, short* __restrict__ Wh, short* __restrict__ Wl)
{
    const size_t idx = ((size_t)blockIdx.x * 256 + threadIdx.x) * 4;
    const float4 v = *(const float4*)&Wm[idx];
    const float f[4] = {v.x, v.y, v.z, v.w};
    short4v h, l;
#pragma unroll
    for (int k = 0; k < 4; ++k) {
        const short hh = f2bf(f[k]);
        h[k] = hh;
        l[k] = f2bf(f[k] - bf2f(hh));
    }
    *(short4v*)&Wh[idx] = h;
    *(short4v*)&Wl[idx] = l;
}

// Wfeh = bf16(-0.5*(Wf + Wf^T))
__global__ __launch_bounds__(256)
void symm_hi(const float* __restrict__ Wf, short* __restrict__ Fh)
{
    const int i  = blockIdx.x;
    const int j0 = threadIdx.x * 4;
    const float4 rv = *(const float4*)&Wf[(size_t)i * 1024 + j0];
    const float c0 = Wf[(size_t)(j0 + 0) * 1024 + i];
    const float c1 = Wf[(size_t)(j0 + 1) * 1024 + i];
    const float c2 = Wf[(size_t)(j0 + 2) * 1024 + i];
    const float c3 = Wf[(size_t)(j0 + 3) * 1024 + i];
    short4v h;
    h[0] = f2bf(-0.5f * (rv.x + c0));
    h[1] = f2bf(-0.5f * (rv.y + c1));
    h[2] = f2bf(-0.5f * (rv.z + c2));
    h[3] = f2bf(-0.5f * (rv.w + c3));
    *(short4v*)&Fh[(size_t)i * 1024 + j0] = h;
}

// ---------------------------------------------------------------------------
extern "C" void kernel_launch(void* const* d_in, const int* in_sizes, int n_in,
                              void* d_out, int out_size, void* d_ws, size_t ws_size,
                              hipStream_t stream)
{
    const float* Y  = (const float*)d_in[0];   // (4096, 1024)
    const float* W  = (const float*)d_in[1];   // (1024, 1024)
    const float* Wf = (const float*)d_in[2];   // (1024, 1024)
    const float* Bb = (const float*)d_in[3];   // (1, 1024)
    float* out = (float*)d_out;

    const int n = 4096, d = 1024;

    // ws layout, 94.4 MB (same as R3/R4):
    char* w = (char*)d_ws;
    short* Ythi = (short*)w; w += (size_t)d * n * 2;   //  8.39 MB
    short* Wfeh = (short*)w; w += (size_t)d * d * 2;   //  2.10 MB
    short* YWth = (short*)w; w += (size_t)n * d * 2;   //  8.39 MB (reused as Zhi)
    short* YWtl = (short*)w; w += (size_t)n * d * 2;   //  8.39 MB
    short* Shi  = (short*)w; w += (size_t)n * n * 2;   // 33.55 MB
    short* Slo  = (short*)w; w += (size_t)n * n * 2;   // 33.55 MB
    // transient split inputs aliased into Shi region (dead before S written):
    short* Yhi = Shi;
    short* Ylo = Yhi + (size_t)n * d;
    short* Whi = Ylo + (size_t)n * d;
    short* Wlo = Whi + (size_t)d * d;
    short* Zhi = YWth;                                  // YWt dead after GEMM2

    split_y<<<dim3(16, 64), 256, 0, stream>>>(Y, Yhi, Ylo, Ythi);
    split_w<<<dim3(1024), 256, 0, stream>>>(W, Whi, Wlo);
    symm_hi<<<dim3(1024), 256, 0, stream>>>(Wf, Wfeh);

    // 1) YWt = Y @ W^T (split 3-product)
    mfma_gemm<true, 0, false><<<dim3(8, 32), 512, 0, stream>>>(
        Yhi, Ylo, Whi, Wlo, nullptr, YWth, YWtl, n, d, d);

    // 2) S = YWt @ YWt^T (split 3-product, symmetric upper-tri + mirror)
    mfma_gemm<true, 0, true><<<dim3(528), 512, 0, stream>>>(
        YWth, YWtl, YWth, YWtl, nullptr, Shi, Slo, n, n, d);

    // 3) A = softmax(S): probabilities as hi-bf16 into Shi
    softmax_hi<<<dim3(n), 256, 0, stream>>>(Shi, Slo);

    // 4) Z = A @ Y (pure bf16 1-product)
    mfma_gemm<false, 1, false><<<dim3(8, 32), 512, 0, stream>>>(
        Shi, nullptr, Ythi, nullptr, nullptr, Zhi, nullptr, n, d, n);

    // 5) out = relu(Z @ Wfe + B) (pure bf16 1-product)
    mfma_gemm<false, 2, false><<<dim3(8, 32), 512, 0, stream>>>(
        Zhi, nullptr, Wfeh, nullptr, Bb, out, nullptr, n, d, d);
}

// Round 8
// 282.552 us; speedup vs baseline: 4.4512x; 1.0632x over previous
//
#include <hip/hip_runtime.h>
#include <cstdint>

// ---------------------------------------------------------------------------
// out = relu((softmax((Y W^T)(Y W^T)^T) @ Y) @ (-0.5(Wf+Wf^T)) + B)
// n=4096, d=1024, fp32 in/out.
// R8 (= R6/R7 resubmit; both hit GPUAcquisitionTimeout, never ran):
//   GEMM2 (S=XX^T): 256^2-tile split-3 kernel, full grid (256 blocks, 1/CU),
//     2-sub-phase K-loop with counted vmcnt(8) across raw barriers,
//     stage-after-certify, setprio MFMA clusters. No SYMM/mirror.
//   GEMM1/3/4: shared 128^2 phase template (64KB LDS -> 2 blocks/CU),
//     counted vmcnt(4), same discipline.
// Fragment/swizzle/epilogue math verbatim from R3/R4 (passed 3x).
// ---------------------------------------------------------------------------

typedef __attribute__((ext_vector_type(8))) short short8;
typedef __attribute__((ext_vector_type(4))) short short4v;
typedef __attribute__((ext_vector_type(4))) float f32x4;

__device__ __forceinline__ short f2bf(float x) {            // RNE fp32 -> bf16
    unsigned u = __builtin_bit_cast(unsigned, x);
    u += 0x7fffu + ((u >> 16) & 1u);
    return (short)(u >> 16);
}
__device__ __forceinline__ float bf2f(short s) {
    unsigned u = ((unsigned)(unsigned short)s) << 16;
    return __builtin_bit_cast(float, u);
}

typedef const __attribute__((address_space(1))) void* gas1_t;
typedef __attribute__((address_space(3))) void* las3_t;
__device__ __forceinline__ void cp16(const void* g, void* l) {
    __builtin_amdgcn_global_load_lds((gas1_t)(uintptr_t)g, (las3_t)(uintptr_t)l, 16, 0, 0);
}

#define MFMA16(A, B, C) __builtin_amdgcn_mfma_f32_16x16x32_bf16(A, B, C, 0, 0, 0)

// ---------------------------------------------------------------------------
// GEMM2 kernel: 256x256 tile, split-3 bf16. C[M,N] = (Ah+Al)[M,K] @ (Bh+Bl)^T.
// 512 thr / 8 waves (2Mx4N), wave tile 128x64, acc[8][4]. BK=32.
// LDS: 2 bufs x (Ah|Al|Bh|Bl planes of [256][32]sh) = 128 KB. 1 block/CU.
// Per K-tile: vmcnt(8) -> bar -> reads(B all + A m0-3) -> MFMA48(m0-3)
//   -> reads(A m4-7) -> lgkm0 -> bar -> stage(t+2) -> MFMA48(m4-7).
// ---------------------------------------------------------------------------
__global__ __launch_bounds__(512, 1)
void gemm256_split(const short* __restrict__ Ah, const short* __restrict__ Al,
                   const short* __restrict__ Bh, const short* __restrict__ Bl,
                   short* __restrict__ Ch, short* __restrict__ Cl,
                   int M, int N, int K)
{
    __shared__ short lds[2][32768];           // 128 KB

    const int tid  = threadIdx.x;
    const int lane = tid & 63;
    const int wave = tid >> 6;
    const int wr   = wave >> 2;               // 0..1  (128-row half)
    const int wc   = wave & 3;                // 0..3  (64-col quarter)

    const int gx  = gridDim.x;
    const int nwg = gx * gridDim.y;
    int lin = blockIdx.y * gx + blockIdx.x;
    if ((nwg & 7) == 0) { const int cpx = nwg >> 3; lin = (lin & 7) * cpx + (lin >> 3); }
    const int bm = (lin / gx) << 8;
    const int bn = (lin % gx) << 8;

    f32x4 acc[8][4];
#pragma unroll
    for (int m = 0; m < 8; ++m)
#pragma unroll
        for (int n = 0; n < 4; ++n)
#pragma unroll
            for (int q = 0; q < 4; ++q) acc[m][n][q] = 0.f;

    // staging: per plane-half (128 rows x 32), thread -> one 16B slot (R4 map)
    const int srow = tid >> 2;                               // 0..127
    const int csw  = (tid & 3) ^ ((tid >> 3) & 3);           // logical chunk
    const size_t oA = (size_t)(bm + srow) * K + csw * 8;
    const size_t oB = (size_t)(bn + srow) * K + csw * 8;
    const short* s0 = Ah + oA; const short* s1 = Al + oA;
    const short* s2 = Bh + oB; const short* s3 = Bl + oB;
    const size_t h128 = (size_t)128 * K;

    auto stage = [&](int t) {                  // 8 cp16 / thread / K-tile
        short* db = &lds[t & 1][0] + tid * 8;
        const int ko = t * 32;
        cp16(s0 + ko, db);          cp16(s0 + h128 + ko, db + 4096);
        cp16(s1 + ko, db + 8192);   cp16(s1 + h128 + ko, db + 12288);
        cp16(s2 + ko, db + 16384);  cp16(s2 + h128 + ko, db + 20480);
        cp16(s3 + ko, db + 24576);  cp16(s3 + h128 + ko, db + 28672);
    };

    // read-side (R3/R4-verified swizzle; row alignment mod 16 preserved)
    const int swz  = ((lane >> 4) ^ ((lane >> 1) & 3)) * 8;
    const int aoff = (wr * 128 + (lane & 15)) * 32 + swz;
    const int boff = (wc * 64  + (lane & 15)) * 32 + swz;

    const int nt = K >> 5;                    // 32 for K=1024
    stage(0); stage(1);

    for (int t = 0; t < nt; ++t) {
        if (t < nt - 1) { asm volatile("s_waitcnt vmcnt(8)" ::: "memory"); }
        else            { asm volatile("s_waitcnt vmcnt(0)" ::: "memory"); }
        __builtin_amdgcn_s_barrier();          // all waves' stage(t) landed
        __builtin_amdgcn_sched_barrier(0);

        const short* base = &lds[t & 1][0];
        short8 fbh[4], fbl[4], fah[4], fal[4];
#pragma unroll
        for (int n = 0; n < 4; ++n) {
            fbh[n] = *(const short8*)(base + 16384 + boff + n * 512);
            fbl[n] = *(const short8*)(base + 24576 + boff + n * 512);
        }
#pragma unroll
        for (int m = 0; m < 4; ++m) {
            fah[m] = *(const short8*)(base + aoff + m * 512);
            fal[m] = *(const short8*)(base + 8192 + aoff + m * 512);
        }
        __builtin_amdgcn_s_setprio(1);
#pragma unroll
        for (int m = 0; m < 4; ++m)
#pragma unroll
            for (int n = 0; n < 4; ++n) {
                acc[m][n] = MFMA16(fah[m], fbh[n], acc[m][n]);
                acc[m][n] = MFMA16(fah[m], fbl[n], acc[m][n]);
                acc[m][n] = MFMA16(fal[m], fbh[n], acc[m][n]);
            }
        __builtin_amdgcn_s_setprio(0);
#pragma unroll
        for (int m = 0; m < 4; ++m) {          // reuse regs for m4-7
            fah[m] = *(const short8*)(base + aoff + (m + 4) * 512);
            fal[m] = *(const short8*)(base + 8192 + aoff + (m + 4) * 512);
        }
        asm volatile("s_waitcnt lgkmcnt(0)" ::: "memory");
        __builtin_amdgcn_sched_barrier(0);
        __builtin_amdgcn_s_barrier();          // all reads of buf[t] done
        __builtin_amdgcn_sched_barrier(0);
        if (t + 2 < nt) stage(t + 2);          // safe: overwrites buf[t]
        __builtin_amdgcn_s_setprio(1);
#pragma unroll
        for (int m = 0; m < 4; ++m)
#pragma unroll
            for (int n = 0; n < 4; ++n) {
                acc[m + 4][n] = MFMA16(fah[m], fbh[n], acc[m + 4][n]);
                acc[m + 4][n] = MFMA16(fah[m], fbl[n], acc[m + 4][n]);
                acc[m + 4][n] = MFMA16(fal[m], fbh[n], acc[m + 4][n]);
            }
        __builtin_amdgcn_s_setprio(0);
    }

    // epilogue: split write. C/D: col = lane&15, row = (lane>>4)*4 + q
    const int crow0 = bm + wr * 128 + ((lane >> 4) << 2);
    const int ccol0 = bn + wc * 64 + (lane & 15);
#pragma unroll
    for (int n = 0; n < 4; ++n) {
        const int c = ccol0 + n * 16;
#pragma unroll
        for (int m = 0; m < 8; ++m)
#pragma unroll
            for (int q = 0; q < 4; ++q) {
                const int r = crow0 + m * 16 + q;
                const float v = acc[m][n][q];
                const short hh = f2bf(v);
                Ch[(size_t)r * N + c] = hh;
                Cl[(size_t)r * N + c] = f2bf(v - bf2f(hh));
            }
    }
}

// ---------------------------------------------------------------------------
// 128x128 phase template (GEMM1/3/4). 512 thr / 8 waves (2Mx4N), wave 64x32,
// acc[4][2]. SPLIT: BK=32, planes Ah|Al|Bh|Bl [128][32]. HI: BK=64, A|B
// [128][64]. LDS 2x32KB = 64 KB -> 2 blocks/CU. counted vmcnt(4).
// OUTMODE: 0 split bf16, 1 hi bf16, 2 f32+bias+relu.
// ---------------------------------------------------------------------------
template<bool SPLIT, int OUTMODE>
__global__ __launch_bounds__(512, 2)
void gemm128_phase(const short* __restrict__ Ah, const short* __restrict__ Al,
                   const short* __restrict__ Bh, const short* __restrict__ Bl,
                   const float* __restrict__ bias, void* Co_, void* Cl_,
                   int M, int N, int K)
{
    constexpr int BK = SPLIT ? 32 : 64;
    __shared__ short lds[2][16384];           // 64 KB

    const int tid  = threadIdx.x;
    const int lane = tid & 63;
    const int wave = tid >> 6;
    const int wr   = wave >> 2;               // 0..1
    const int wc   = wave & 3;                // 0..3

    const int gx  = gridDim.x;
    const int nwg = gx * gridDim.y;
    int lin = blockIdx.y * gx + blockIdx.x;
    if ((nwg & 7) == 0) { const int cpx = nwg >> 3; lin = (lin & 7) * cpx + (lin >> 3); }
    const int bm = (lin / gx) << 7;
    const int bn = (lin % gx) << 7;

    f32x4 acc[4][2];
#pragma unroll
    for (int m = 0; m < 4; ++m)
#pragma unroll
        for (int n = 0; n < 2; ++n)
#pragma unroll
            for (int q = 0; q < 4; ++q) acc[m][n][q] = 0.f;

    // staging sources: 4 cp16/thread/K-tile (R4-verified maps)
    const short *p0, *p1, *p2, *p3;
    if constexpr (SPLIT) {
        const int row = tid >> 2;                        // 0..127
        const int c4  = (tid & 3) ^ ((tid >> 3) & 3);
        const size_t oA = (size_t)(bm + row) * K + c4 * 8;
        const size_t oB = (size_t)(bn + row) * K + c4 * 8;
        p0 = Ah + oA; p1 = Al + oA; p2 = Bh + oB; p3 = Bl + oB;
    } else {
        const int row = tid >> 3;                        // 0..63
        const int lch = (tid & 7) ^ ((tid >> 3) & 7);
        const size_t oA = (size_t)(bm + row) * K + lch * 8;
        const size_t oB = (size_t)(bn + row) * K + lch * 8;
        p0 = Ah + oA; p1 = p0 + (size_t)64 * K;
        p2 = Bh + oB; p3 = p2 + (size_t)64 * K;
    }

    auto stage = [&](int t) {
        short* db = &lds[t & 1][0] + tid * 8;
        const int ko = t * BK;
        cp16(p0 + ko, db);
        cp16(p1 + ko, db + 4096);
        cp16(p2 + ko, db + 8192);
        cp16(p3 + ko, db + 12288);
    };

    int aoff, boff;
    if constexpr (SPLIT) {
        const int swz = ((lane >> 4) ^ ((lane >> 1) & 3)) * 8;
        aoff = (wr * 64 + (lane & 15)) * 32 + swz;
        boff = (wc * 32 + (lane & 15)) * 32 + swz;
    } else {
        aoff = (wr * 64 + (lane & 15)) * 64;
        boff = (wc * 32 + (lane & 15)) * 64;
    }

    const int nt = K / BK;
    stage(0); stage(1);

    for (int t = 0; t < nt; ++t) {
        if (t < nt - 1) { asm volatile("s_waitcnt vmcnt(4)" ::: "memory"); }
        else            { asm volatile("s_waitcnt vmcnt(0)" ::: "memory"); }
        __builtin_amdgcn_s_barrier();
        __builtin_amdgcn_sched_barrier(0);

        const short* base = &lds[t & 1][0];
        if constexpr (SPLIT) {
            short8 fah[4], fal[4], fbh[2], fbl[2];
#pragma unroll
            for (int n = 0; n < 2; ++n) {
                fbh[n] = *(const short8*)(base + 8192  + boff + n * 512);
                fbl[n] = *(const short8*)(base + 12288 + boff + n * 512);
            }
#pragma unroll
            for (int m = 0; m < 4; ++m) {
                fah[m] = *(const short8*)(base + aoff + m * 512);
                fal[m] = *(const short8*)(base + 4096 + aoff + m * 512);
            }
            __builtin_amdgcn_s_setprio(1);
#pragma unroll
            for (int m = 0; m < 2; ++m)
#pragma unroll
                for (int n = 0; n < 2; ++n) {
                    acc[m][n] = MFMA16(fah[m], fbh[n], acc[m][n]);
                    acc[m][n] = MFMA16(fah[m], fbl[n], acc[m][n]);
                    acc[m][n] = MFMA16(fal[m], fbh[n], acc[m][n]);
                }
            __builtin_amdgcn_s_setprio(0);
            asm volatile("s_waitcnt lgkmcnt(0)" ::: "memory");
            __builtin_amdgcn_sched_barrier(0);
            __builtin_amdgcn_s_barrier();
            __builtin_amdgcn_sched_barrier(0);
            if (t + 2 < nt) stage(t + 2);
            __builtin_amdgcn_s_setprio(1);
#pragma unroll
            for (int m = 2; m < 4; ++m)
#pragma unroll
                for (int n = 0; n < 2; ++n) {
                    acc[m][n] = MFMA16(fah[m], fbh[n], acc[m][n]);
                    acc[m][n] = MFMA16(fah[m], fbl[n], acc[m][n]);
                    acc[m][n] = MFMA16(fal[m], fbh[n], acc[m][n]);
                }
            __builtin_amdgcn_s_setprio(0);
        } else {
            short8 fa[2][4], fb[2][2];
#pragma unroll
            for (int ks = 0; ks < 2; ++ks) {
                const int sw = ((ks * 4 + (lane >> 4)) ^ (lane & 7)) * 8;
#pragma unroll
                for (int m = 0; m < 4; ++m)
                    fa[ks][m] = *(const short8*)(base + aoff + sw + m * 1024);
#pragma unroll
                for (int n = 0; n < 2; ++n)
                    fb[ks][n] = *(const short8*)(base + 8192 + boff + sw + n * 1024);
            }
            __builtin_amdgcn_s_setprio(1);
#pragma unroll
            for (int m = 0; m < 4; ++m)
#pragma unroll
                for (int n = 0; n < 2; ++n)
                    acc[m][n] = MFMA16(fa[0][m], fb[0][n], acc[m][n]);
            __builtin_amdgcn_s_setprio(0);
            asm volatile("s_waitcnt lgkmcnt(0)" ::: "memory");
            __builtin_amdgcn_sched_barrier(0);
            __builtin_amdgcn_s_barrier();
            __builtin_amdgcn_sched_barrier(0);
            if (t + 2 < nt) stage(t + 2);
            __builtin_amdgcn_s_setprio(1);
#pragma unroll
            for (int m = 0; m < 4; ++m)
#pragma unroll
                for (int n = 0; n < 2; ++n)
                    acc[m][n] = MFMA16(fa[1][m], fb[1][n], acc[m][n]);
            __builtin_amdgcn_s_setprio(0);
        }
    }

    // epilogue: C/D layout col = lane&15, row = (lane>>4)*4 + q
    const int crow0 = bm + wr * 64 + ((lane >> 4) << 2);
    const int ccol0 = bn + wc * 32 + (lane & 15);
    if constexpr (OUTMODE == 2) {
        float* C = (float*)Co_;
#pragma unroll
        for (int n = 0; n < 2; ++n) {
            const int c = ccol0 + n * 16;
            const float bv = bias[c];
#pragma unroll
            for (int m = 0; m < 4; ++m)
#pragma unroll
                for (int q = 0; q < 4; ++q) {
                    const int r = crow0 + m * 16 + q;
                    C[(size_t)r * N + c] = fmaxf(acc[m][n][q] + bv, 0.f);
                }
        }
    } else if constexpr (OUTMODE == 1) {
        short* Ch = (short*)Co_;
#pragma unroll
        for (int n = 0; n < 2; ++n) {
            const int c = ccol0 + n * 16;
#pragma unroll
            for (int m = 0; m < 4; ++m)
#pragma unroll
                for (int q = 0; q < 4; ++q) {
                    const int r = crow0 + m * 16 + q;
                    Ch[(size_t)r * N + c] = f2bf(acc[m][n][q]);
                }
        }
    } else {
        short* Ch = (short*)Co_;
        short* Cl = (short*)Cl_;
#pragma unroll
        for (int n = 0; n < 2; ++n) {
            const int c = ccol0 + n * 16;
#pragma unroll
            for (int m = 0; m < 4; ++m)
#pragma unroll
                for (int q = 0; q < 4; ++q) {
                    const int r = crow0 + m * 16 + q;
                    const float v = acc[m][n][q];
                    const short hh = f2bf(v);
                    Ch[(size_t)r * N + c] = hh;
                    Cl[(size_t)r * N + c] = f2bf(v - bf2f(hh));
                }
        }
    }
}

// ---------------------------------------------------------------------------
// Row softmax over split logits; writes PROBABILITIES as hi-bf16 into Shi.
// ---------------------------------------------------------------------------
__global__ __launch_bounds__(256)
void softmax_hi(short* __restrict__ Shi, const short* __restrict__ Slo)
{
    const int row = blockIdx.x;
    short8* ph = (short8*)(Shi + (size_t)row * 4096);
    const short8* pl = (const short8*)(Slo + (size_t)row * 4096);
    const int t = threadIdx.x;

    short8 h0 = ph[t], h1 = ph[t + 256];
    short8 l0 = pl[t], l1 = pl[t + 256];
    float x[16];
#pragma unroll
    for (int j = 0; j < 8; ++j) {
        x[j]     = bf2f(h0[j]) + bf2f(l0[j]);
        x[8 + j] = bf2f(h1[j]) + bf2f(l1[j]);
    }
    float mx = x[0];
#pragma unroll
    for (int j = 1; j < 16; ++j) mx = fmaxf(mx, x[j]);
#pragma unroll
    for (int off = 32; off > 0; off >>= 1) mx = fmaxf(mx, __shfl_xor(mx, off));

    __shared__ float rm[4], rs[4];
    const int wv = t >> 6, ln = t & 63;
    if (ln == 0) rm[wv] = mx;
    __syncthreads();
    mx = fmaxf(fmaxf(rm[0], rm[1]), fmaxf(rm[2], rm[3]));

    float s = 0.f;
#pragma unroll
    for (int j = 0; j < 16; ++j) { x[j] = __expf(x[j] - mx); s += x[j]; }
#pragma unroll
    for (int off = 32; off > 0; off >>= 1) s += __shfl_xor(s, off);
    if (ln == 0) rs[wv] = s;
    __syncthreads();
    s = rs[0] + rs[1] + rs[2] + rs[3];

    const float inv = 1.f / s;
    short8 o0, o1;
#pragma unroll
    for (int j = 0; j < 8; ++j) {
        o0[j] = f2bf(x[j] * inv);
        o1[j] = f2bf(x[8 + j] * inv);
    }
    ph[t] = o0; ph[t + 256] = o1;
}

// ---------------------------------------------------------------------------
// Y (4096x1024 f32) -> Yhi/Ylo (row-major split) + Ythi (transposed hi bf16)
// ---------------------------------------------------------------------------
__global__ __launch_bounds__(256)
void split_y(const float* __restrict__ Y, short* __restrict__ Yhi,
             short* __restrict__ Ylo, short* __restrict__ Yt)
{
    __shared__ float tb[64][65];
    const int rb = blockIdx.y * 64, cb = blockIdx.x * 64;
    const int t = threadIdx.x;
    const int r = t >> 4, c4 = (t & 15) * 4;
#pragma unroll
    for (int it = 0; it < 4; ++it) {
        const int row = rb + r + it * 16;
        const float4 v = *(const float4*)&Y[(size_t)row * 1024 + cb + c4];
        const float f[4] = {v.x, v.y, v.z, v.w};
        short4v h, l;
#pragma unroll
        for (int k = 0; k < 4; ++k) {
            const short hh = f2bf(f[k]);
            h[k] = hh;
            l[k] = f2bf(f[k] - bf2f(hh));
        }
        *(short4v*)&Yhi[(size_t)row * 1024 + cb + c4] = h;
        *(short4v*)&Ylo[(size_t)row * 1024 + cb + c4] = l;
        tb[r + it * 16][c4 + 0] = v.x; tb[r + it * 16][c4 + 1] = v.y;
        tb[r + it * 16][c4 + 2] = v.z; tb[r + it * 16][c4 + 3] = v.w;
    }
    __syncthreads();
    const int orow = t >> 2, oc0 = (t & 3) * 16;
    short8 h8[2];
#pragma unroll
    for (int g = 0; g < 2; ++g)
#pragma unroll
        for (int j = 0; j < 8; ++j)
            h8[g][j] = f2bf(tb[oc0 + g * 8 + j][orow]);
    const size_t ob = (size_t)(cb + orow) * 4096 + rb + oc0;
    *(short8*)&Yt[ob] = h8[0];
    *(short8*)&Yt[ob + 8] = h8[1];
}

// W (1024x1024 f32) -> Whi/Wlo
__global__ __launch_bounds__(256)
void split_w(const float* __restrict__ Wm, short* __restrict__ Wh, short* __restrict__ Wl)
{
    const size_t idx = ((size_t)blockIdx.x * 256 + threadIdx.x) * 4;
    const float4 v = *(const float4*)&Wm[idx];
    const float f[4] = {v.x, v.y, v.z, v.w};
    short4v h, l;
#pragma unroll
    for (int k = 0; k < 4; ++k) {
        const short hh = f2bf(f[k]);
        h[k] = hh;
        l[k] = f2bf(f[k] - bf2f(hh));
    }
    *(short4v*)&Wh[idx] = h;
    *(short4v*)&Wl[idx] = l;
}

// Wfeh = bf16(-0.5*(Wf + Wf^T))
__global__ __launch_bounds__(256)
void symm_hi(const float* __restrict__ Wf, short* __restrict__ Fh)
{
    const int i  = blockIdx.x;
    const int j0 = threadIdx.x * 4;
    const float4 rv = *(const float4*)&Wf[(size_t)i * 1024 + j0];
    const float c0 = Wf[(size_t)(j0 + 0) * 1024 + i];
    const float c1 = Wf[(size_t)(j0 + 1) * 1024 + i];
    const float c2 = Wf[(size_t)(j0 + 2) * 1024 + i];
    const float c3 = Wf[(size_t)(j0 + 3) * 1024 + i];
    short4v h;
    h[0] = f2bf(-0.5f * (rv.x + c0));
    h[1] = f2bf(-0.5f * (rv.y + c1));
    h[2] = f2bf(-0.5f * (rv.z + c2));
    h[3] = f2bf(-0.5f * (rv.w + c3));
    *(short4v*)&Fh[(size_t)i * 1024 + j0] = h;
}

// ---------------------------------------------------------------------------
extern "C" void kernel_launch(void* const* d_in, const int* in_sizes, int n_in,
                              void* d_out, int out_size, void* d_ws, size_t ws_size,
                              hipStream_t stream)
{
    const float* Y  = (const float*)d_in[0];   // (4096, 1024)
    const float* W  = (const float*)d_in[1];   // (1024, 1024)
    const float* Wf = (const float*)d_in[2];   // (1024, 1024)
    const float* Bb = (const float*)d_in[3];   // (1, 1024)
    float* out = (float*)d_out;

    const int n = 4096, d = 1024;

    // ws layout, 94.4 MB (same as R3-R5):
    char* w = (char*)d_ws;
    short* Ythi = (short*)w; w += (size_t)d * n * 2;   //  8.39 MB
    short* Wfeh = (short*)w; w += (size_t)d * d * 2;   //  2.10 MB
    short* YWth = (short*)w; w += (size_t)n * d * 2;   //  8.39 MB (reused as Zhi)
    short* YWtl = (short*)w; w += (size_t)n * d * 2;   //  8.39 MB
    short* Shi  = (short*)w; w += (size_t)n * n * 2;   // 33.55 MB
    short* Slo  = (short*)w; w += (size_t)n * n * 2;   // 33.55 MB
    // transient split inputs aliased into Shi region (dead before S written):
    short* Yhi = Shi;
    short* Ylo = Yhi + (size_t)n * d;
    short* Whi = Ylo + (size_t)n * d;
    short* Wlo = Whi + (size_t)d * d;
    short* Zhi = YWth;                                  // YWt dead after GEMM2

    split_y<<<dim3(16, 64), 256, 0, stream>>>(Y, Yhi, Ylo, Ythi);
    split_w<<<dim3(1024), 256, 0, stream>>>(W, Whi, Wlo);
    symm_hi<<<dim3(1024), 256, 0, stream>>>(Wf, Wfeh);

    // 1) YWt = Y @ W^T (split 3-product, 128^2 phase template)
    gemm128_phase<true, 0><<<dim3(8, 32), 512, 0, stream>>>(
        Yhi, Ylo, Whi, Wlo, nullptr, YWth, YWtl, n, d, d);

    // 2) S = YWt @ YWt^T (split 3-product, 256^2 full grid)
    gemm256_split<<<dim3(16, 16), 512, 0, stream>>>(
        YWth, YWtl, YWth, YWtl, Shi, Slo, n, n, d);

    // 3) A = softmax(S): probabilities as hi-bf16 into Shi
    softmax_hi<<<dim3(n), 256, 0, stream>>>(Shi, Slo);

    // 4) Z = A @ Y (pure bf16 1-product)
    gemm128_phase<false, 1><<<dim3(8, 32), 512, 0, stream>>>(
        Shi, nullptr, Ythi, nullptr, nullptr, Zhi, nullptr, n, d, n);

    // 5) out = relu(Z @ Wfe + B) (pure bf16 1-product)
    gemm128_phase<false, 2><<<dim3(8, 32), 512, 0, stream>>>(
        Zhi, nullptr, Wfeh, nullptr, Bb, out, nullptr, n, d, d);
}